// Round 7
// baseline (392.594 us; speedup 1.0000x reference)
//
#include <hip/hip_runtime.h>
#include <stdint.h>

// VectorQuantizer: z [32768,64], codebook [1024,64] (dtype sniffed bf16/f32).
// d_out FLOAT32: z_q_st [2097152] ++ loss [1] ++ indices [32768].
// Bit-exact replication of the reference f32 arithmetic (numpy pairwise sums,
// sequential non-fused dot, f32 final adds, first-index argmin).
//
// R10 vs R9 (316us): R9's reg-buffer pipeline was deleted by the allocator
// (VGPR stayed 80). Model now exact: bf16 scan issue-floor 82us, VALUBusy 26%
// == floor/measured -> latency-bound, too few waves. Changes:
//  1) prep converts bf16 codebook -> f32 image in workspace (ws_size-gated);
//     scan always runs the f32 path: 2 inst/elem (no unpack), floor ~55us.
//  2) grid 2048 blocks (16 rows x 16 parts, 64 codes/thread) -> residency
//     VGPR-capped (~5 blocks/CU), not grid-capped.
//  3) keep R8's 4-chain ILP + fine part interleave + lex (d2,k) merge.
#define N_ROWS 32768
#define DIM 64
#define K_CODES 1024
#define ROWS_PER_BLOCK 16
#define PARTS 16
#define CODES_PER_THREAD (K_CODES / PARTS)    // 64
#define NGROUPS (CODES_PER_THREAD / 4)        // 16 groups of 4 codes
#define NBLOCKS (N_ROWS / ROWS_PER_BLOCK)     // 2048
#define N_ELEMS (N_ROWS * DIM)                // 2097152

// workspace layout (bytes):
// [0,4096)        float cc[1024]
// [4096,4100)     int flags  (bit0: z is bf16, bit1: cb is bf16)
// [8192,24576)    double partials[NBLOCKS=2048]
// [24576,286720)  float cbf32[1024*64]  (only if ws_size >= 286720)
#define WS_CBF_OFF 24576
#define WS_NEED (WS_CBF_OFF + K_CODES * DIM * 4)

__device__ __forceinline__ float bfbits(uint32_t b) { return __uint_as_float(b << 16); }
__device__ __forceinline__ float bf_lo(uint32_t u) { return __uint_as_float(u << 16); }
__device__ __forceinline__ float bf_hi(uint32_t u) { return __uint_as_float(u & 0xFFFF0000u); }

// round f32 -> nearest bf16 value, returned AS f32 (RNE; finite inputs).
// Idempotent on values already on the bf16 grid.
__device__ __forceinline__ float round_bf16(float f) {
  uint32_t u = __float_as_uint(f);
  uint32_t r = ((u + 0x7FFFu + ((u >> 16) & 1u)) >> 16) << 16;
  return __uint_as_float(r);
}

// numpy pairwise_sum for n=64 (8 accumulators, 8 rounds, numpy's combine tree).
template <typename F>
__device__ __forceinline__ float np_sum64(F get) {
  float r0 = get(0), r1 = get(1), r2 = get(2), r3 = get(3);
  float r4 = get(4), r5 = get(5), r6 = get(6), r7 = get(7);
  for (int i = 8; i < 64; i += 8) {
    r0 = __fadd_rn(r0, get(i + 0)); r1 = __fadd_rn(r1, get(i + 1));
    r2 = __fadd_rn(r2, get(i + 2)); r3 = __fadd_rn(r3, get(i + 3));
    r4 = __fadd_rn(r4, get(i + 4)); r5 = __fadd_rn(r5, get(i + 5));
    r6 = __fadd_rn(r6, get(i + 6)); r7 = __fadd_rn(r7, get(i + 7));
  }
  return __fadd_rn(__fadd_rn(__fadd_rn(r0, r1), __fadd_rn(r2, r3)),
                   __fadd_rn(__fadd_rn(r4, r5), __fadd_rn(r6, r7)));
}

// Precompute: dtype sniff + cc_k = np.sum(c*c) per code + optional bf16->f32
// codebook image (cbf_out != null and cb is bf16).
__global__ __launch_bounds__(256) void vq_prep_kernel(
    const void* __restrict__ z, const void* __restrict__ cb,
    float* __restrict__ cc_out, int* __restrict__ flags,
    float* __restrict__ cbf_out) {
  const int tid = threadIdx.x;
  __shared__ int s_cnt[2];
  if (tid < 2) s_cnt[tid] = 0;
  __syncthreads();
  if (tid < 128) {
    uint32_t wc = ((const uint32_t*)cb)[(size_t)tid * 255];
    float vc = fabsf(bfbits(wc & 0xFFFFu));
    if (vc == 0.0f || (vc > 5.9e-8f && vc < 32.0f)) atomicAdd(&s_cnt[1], 1);
    if (blockIdx.x == 0) {
      uint32_t wz = ((const uint32_t*)z)[(size_t)tid * 8191];
      float vz = fabsf(bfbits(wz & 0xFFFFu));
      if (vz == 0.0f || (vz > 5.9e-8f && vz < 32.0f)) atomicAdd(&s_cnt[0], 1);
    }
  }
  __syncthreads();
  const bool cb_bf16 = s_cnt[1] >= 96;
  if (blockIdx.x == 0 && tid == 0)
    flags[0] = (s_cnt[0] >= 96 ? 1 : 0) | (cb_bf16 ? 2 : 0);

  const int kk = blockIdx.x * 256 + tid;
  float v;
  if (cb_bf16) {
    const uint16_t* cp = (const uint16_t*)cb + (size_t)kk * DIM;
    v = np_sum64([&](int d) { float c = bfbits((uint32_t)cp[d]);
                              return __fmul_rn(c, c); });
  } else {
    const float* cp = (const float*)cb + (size_t)kk * DIM;
    v = np_sum64([&](int d) { return __fmul_rn(cp[d], cp[d]); });
  }
  cc_out[kk] = v;

  // bf16 -> f32 codebook image (exact values). Block b: uint4 [b*2048,b*2048+2048).
  if (cb_bf16 && cbf_out != nullptr) {
    const uint4* src = (const uint4*)cb;
    float4* dst = (float4*)cbf_out;
    #pragma unroll
    for (int j = 0; j < 8; ++j) {
      int idx = blockIdx.x * 2048 + tid + 256 * j;
      uint4 u = src[idx];
      float4 lo, hi;
      lo.x = bf_lo(u.x); lo.y = bf_hi(u.x);
      lo.z = bf_lo(u.y); lo.w = bf_hi(u.y);
      hi.x = bf_lo(u.z); hi.y = bf_hi(u.z);
      hi.z = bf_lo(u.w); hi.w = bf_hi(u.w);
      dst[idx * 2] = lo;
      dst[idx * 2 + 1] = hi;
    }
  }
}

// Thread = (row r = tid&15, part = tid>>4); part p scans codes 64g+4p+j
// (g=0..15, j=0..3) ascending. idx in [0,64) -> k = 64*(idx>>2)+4p+(idx&3).
__device__ __forceinline__ int kidx(int idx, int part) {
  return ((idx >> 2) << 6) + (part << 2) + (idx & 3);
}

__global__ __launch_bounds__(256) void vq_kernel(
    const void* __restrict__ z, const void* __restrict__ cb,
    const float* __restrict__ cbf_ws, const int use_ws,
    const float* __restrict__ cc_in, const int* __restrict__ flags,
    float* __restrict__ out, double* __restrict__ partials) {
  const int tid = threadIdx.x;
  const int fl = flags[0];
  const bool z_bf16  = (fl & 1) != 0;
  const bool cb_bf16 = (fl & 2) != 0;
  // f32 image of the codebook (exact input values), when available.
  const float* cbf = !cb_bf16 ? (const float*)cb : (use_ws ? cbf_ws : nullptr);

  __shared__ float s_cc[K_CODES];                 // 4 KB
  __shared__ float s_best[256];
  __shared__ int s_k[256];
  __shared__ int s_win[ROWS_PER_BLOCK];
  __shared__ double s_loss[ROWS_PER_BLOCK];

  #pragma unroll
  for (int kk = tid; kk < K_CODES; kk += 256) s_cc[kk] = cc_in[kk];

  const int r = tid & (ROWS_PER_BLOCK - 1);
  const int part = tid >> 4;
  const size_t row = (size_t)blockIdx.x * ROWS_PER_BLOCK + r;

  // Load z row as exact f32 values (vectorized).
  float zf[DIM];
  if (z_bf16) {
    const uint4* p = (const uint4*)((const uint16_t*)z + row * DIM);
    #pragma unroll
    for (int j = 0; j < 8; ++j) {
      uint4 u = p[j];
      zf[j * 8 + 0] = bf_lo(u.x); zf[j * 8 + 1] = bf_hi(u.x);
      zf[j * 8 + 2] = bf_lo(u.y); zf[j * 8 + 3] = bf_hi(u.y);
      zf[j * 8 + 4] = bf_lo(u.z); zf[j * 8 + 5] = bf_hi(u.z);
      zf[j * 8 + 6] = bf_lo(u.w); zf[j * 8 + 7] = bf_hi(u.w);
    }
  } else {
    const float4* p = (const float4*)((const float*)z + row * DIM);
    #pragma unroll
    for (int j = 0; j < 16; ++j) {
      float4 v = p[j];
      zf[j * 4 + 0] = v.x; zf[j * 4 + 1] = v.y;
      zf[j * 4 + 2] = v.z; zf[j * 4 + 3] = v.w;
    }
  }
  // zz = np.sum(z*z, axis=1) in f32, numpy pairwise order.
  const float zz = np_sum64([&](int d) { return __fmul_rn(zf[d], zf[d]); });

  __syncthreads();  // s_cc ready

  // Scan: d2 = fl(fl(zz + cc_k) - fl(2*g)), g = sequential f32 dot ascending d
  // (einsum inner loop, non-fused). Per-thread k ascending, strict < (np ties).
  float best = 3.4e38f;
  int bk = 0;

  if (cbf != nullptr) {
    // f32 scan: 2 VALU inst/elem, 4 independent chains.
    for (int gi = 0; gi < NGROUPS; ++gi) {
      const int k = (gi << 6) + (part << 2);
      const float4* c0 = (const float4*)(cbf + (size_t)(k + 0) * DIM);
      const float4* c1 = (const float4*)(cbf + (size_t)(k + 1) * DIM);
      const float4* c2 = (const float4*)(cbf + (size_t)(k + 2) * DIM);
      const float4* c3 = (const float4*)(cbf + (size_t)(k + 3) * DIM);
      float g0 = 0.0f, g1 = 0.0f, g2 = 0.0f, g3 = 0.0f;
      #pragma unroll
      for (int j = 0; j < 16; ++j) {
        float4 a = c0[j], b = c1[j], cc2 = c2[j], dd = c3[j];
        const int d0 = j * 4;
        g0 = __fadd_rn(g0, __fmul_rn(zf[d0 + 0], a.x));
        g0 = __fadd_rn(g0, __fmul_rn(zf[d0 + 1], a.y));
        g0 = __fadd_rn(g0, __fmul_rn(zf[d0 + 2], a.z));
        g0 = __fadd_rn(g0, __fmul_rn(zf[d0 + 3], a.w));
        g1 = __fadd_rn(g1, __fmul_rn(zf[d0 + 0], b.x));
        g1 = __fadd_rn(g1, __fmul_rn(zf[d0 + 1], b.y));
        g1 = __fadd_rn(g1, __fmul_rn(zf[d0 + 2], b.z));
        g1 = __fadd_rn(g1, __fmul_rn(zf[d0 + 3], b.w));
        g2 = __fadd_rn(g2, __fmul_rn(zf[d0 + 0], cc2.x));
        g2 = __fadd_rn(g2, __fmul_rn(zf[d0 + 1], cc2.y));
        g2 = __fadd_rn(g2, __fmul_rn(zf[d0 + 2], cc2.z));
        g2 = __fadd_rn(g2, __fmul_rn(zf[d0 + 3], cc2.w));
        g3 = __fadd_rn(g3, __fmul_rn(zf[d0 + 0], dd.x));
        g3 = __fadd_rn(g3, __fmul_rn(zf[d0 + 1], dd.y));
        g3 = __fadd_rn(g3, __fmul_rn(zf[d0 + 2], dd.z));
        g3 = __fadd_rn(g3, __fmul_rn(zf[d0 + 3], dd.w));
      }
      float e0 = __fsub_rn(__fadd_rn(zz, s_cc[k + 0]), __fmul_rn(2.0f, g0));
      float e1 = __fsub_rn(__fadd_rn(zz, s_cc[k + 1]), __fmul_rn(2.0f, g1));
      float e2 = __fsub_rn(__fadd_rn(zz, s_cc[k + 2]), __fmul_rn(2.0f, g2));
      float e3 = __fsub_rn(__fadd_rn(zz, s_cc[k + 3]), __fmul_rn(2.0f, g3));
      if (e0 < best) { best = e0; bk = k + 0; }
      if (e1 < best) { best = e1; bk = k + 1; }
      if (e2 < best) { best = e2; bk = k + 2; }
      if (e3 < best) { best = e3; bk = k + 3; }
    }
  } else {
    // bf16 fallback (cb bf16, workspace too small): R8 structure.
    const uint4* cb4 = (const uint4*)cb;      // 8 uint4 per code
    for (int gi = 0; gi < NGROUPS; ++gi) {
      const int k = (gi << 6) + (part << 2);
      const uint4* c0 = cb4 + (size_t)(k + 0) * 8;
      const uint4* c1 = cb4 + (size_t)(k + 1) * 8;
      const uint4* c2 = cb4 + (size_t)(k + 2) * 8;
      const uint4* c3 = cb4 + (size_t)(k + 3) * 8;
      float g0 = 0.0f, g1 = 0.0f, g2 = 0.0f, g3 = 0.0f;
      #pragma unroll
      for (int j = 0; j < 8; ++j) {
        uint4 u0 = c0[j], u1 = c1[j], u2 = c2[j], u3 = c3[j];
        const int d0 = j * 8;
        g0 = __fadd_rn(g0, __fmul_rn(zf[d0 + 0], bf_lo(u0.x)));
        g0 = __fadd_rn(g0, __fmul_rn(zf[d0 + 1], bf_hi(u0.x)));
        g0 = __fadd_rn(g0, __fmul_rn(zf[d0 + 2], bf_lo(u0.y)));
        g0 = __fadd_rn(g0, __fmul_rn(zf[d0 + 3], bf_hi(u0.y)));
        g0 = __fadd_rn(g0, __fmul_rn(zf[d0 + 4], bf_lo(u0.z)));
        g0 = __fadd_rn(g0, __fmul_rn(zf[d0 + 5], bf_hi(u0.z)));
        g0 = __fadd_rn(g0, __fmul_rn(zf[d0 + 6], bf_lo(u0.w)));
        g0 = __fadd_rn(g0, __fmul_rn(zf[d0 + 7], bf_hi(u0.w)));
        g1 = __fadd_rn(g1, __fmul_rn(zf[d0 + 0], bf_lo(u1.x)));
        g1 = __fadd_rn(g1, __fmul_rn(zf[d0 + 1], bf_hi(u1.x)));
        g1 = __fadd_rn(g1, __fmul_rn(zf[d0 + 2], bf_lo(u1.y)));
        g1 = __fadd_rn(g1, __fmul_rn(zf[d0 + 3], bf_hi(u1.y)));
        g1 = __fadd_rn(g1, __fmul_rn(zf[d0 + 4], bf_lo(u1.z)));
        g1 = __fadd_rn(g1, __fmul_rn(zf[d0 + 5], bf_hi(u1.z)));
        g1 = __fadd_rn(g1, __fmul_rn(zf[d0 + 6], bf_lo(u1.w)));
        g1 = __fadd_rn(g1, __fmul_rn(zf[d0 + 7], bf_hi(u1.w)));
        g2 = __fadd_rn(g2, __fmul_rn(zf[d0 + 0], bf_lo(u2.x)));
        g2 = __fadd_rn(g2, __fmul_rn(zf[d0 + 1], bf_hi(u2.x)));
        g2 = __fadd_rn(g2, __fmul_rn(zf[d0 + 2], bf_lo(u2.y)));
        g2 = __fadd_rn(g2, __fmul_rn(zf[d0 + 3], bf_hi(u2.y)));
        g2 = __fadd_rn(g2, __fmul_rn(zf[d0 + 4], bf_lo(u2.z)));
        g2 = __fadd_rn(g2, __fmul_rn(zf[d0 + 5], bf_hi(u2.z)));
        g2 = __fadd_rn(g2, __fmul_rn(zf[d0 + 6], bf_lo(u2.w)));
        g2 = __fadd_rn(g2, __fmul_rn(zf[d0 + 7], bf_hi(u2.w)));
        g3 = __fadd_rn(g3, __fmul_rn(zf[d0 + 0], bf_lo(u3.x)));
        g3 = __fadd_rn(g3, __fmul_rn(zf[d0 + 1], bf_hi(u3.x)));
        g3 = __fadd_rn(g3, __fmul_rn(zf[d0 + 2], bf_lo(u3.y)));
        g3 = __fadd_rn(g3, __fmul_rn(zf[d0 + 3], bf_hi(u3.y)));
        g3 = __fadd_rn(g3, __fmul_rn(zf[d0 + 4], bf_lo(u3.z)));
        g3 = __fadd_rn(g3, __fmul_rn(zf[d0 + 5], bf_hi(u3.z)));
        g3 = __fadd_rn(g3, __fmul_rn(zf[d0 + 6], bf_lo(u3.w)));
        g3 = __fadd_rn(g3, __fmul_rn(zf[d0 + 7], bf_hi(u3.w)));
      }
      float e0 = __fsub_rn(__fadd_rn(zz, s_cc[k + 0]), __fmul_rn(2.0f, g0));
      float e1 = __fsub_rn(__fadd_rn(zz, s_cc[k + 1]), __fmul_rn(2.0f, g1));
      float e2 = __fsub_rn(__fadd_rn(zz, s_cc[k + 2]), __fmul_rn(2.0f, g2));
      float e3 = __fsub_rn(__fadd_rn(zz, s_cc[k + 3]), __fmul_rn(2.0f, g3));
      if (e0 < best) { best = e0; bk = k + 0; }
      if (e1 < best) { best = e1; bk = k + 1; }
      if (e2 < best) { best = e2; bk = k + 2; }
      if (e3 < best) { best = e3; bk = k + 3; }
    }
  }

  s_best[tid] = best;
  s_k[tid] = bk;
  __syncthreads();

  if (tid < ROWS_PER_BLOCK) {
    // Parts interleave k -> merge with lexicographic (d2, k): exactly the
    // global first-index (numpy) argmin.
    float b = 3.4e38f;
    int bbk = 0x7FFFFFFF;
    for (int p = 0; p < PARTS; ++p) {
      float v = s_best[p * ROWS_PER_BLOCK + tid];
      int vk = s_k[p * ROWS_PER_BLOCK + tid];
      if (v < b || (v == b && vk < bbk)) { b = v; bbk = vk; }
    }
    s_win[tid] = bbk;
    // Exact squared distance of the winner (fp64) — thread tid owns row tid's
    // zf (tid < 16 => r == tid, part == 0).
    double acc = 0.0;
    if (cbf != nullptr) {
      const float* cp = cbf + (size_t)bbk * DIM;
      for (int d = 0; d < DIM; ++d) {
        double df = (double)zf[d] - (double)cp[d];
        acc = fma(df, df, acc);
      }
    } else {
      const uint16_t* cp = (const uint16_t*)cb + (size_t)bbk * DIM;
      for (int d = 0; d < DIM; ++d) {
        double df = (double)zf[d] - (double)bfbits((uint32_t)cp[d]);
        acc = fma(df, df, acc);
      }
    }
    s_loss[tid] = acc;
    const size_t myrow = (size_t)blockIdx.x * ROWS_PER_BLOCK + tid;
    out[(size_t)N_ELEMS + 1 + myrow] = round_bf16((float)bbk);
  }
  __syncthreads();

  // z_q write: 16 rows x 64 dims = 1024 floats, 256 threads x 4, coalesced.
  // round_bf16 is idempotent on bf16-grid values -> correct for both paths.
  const size_t base = (size_t)blockIdx.x * ROWS_PER_BLOCK * DIM;
  #pragma unroll
  for (int j = 0; j < 4; ++j) {
    int idx = tid + 256 * j;
    int rr = idx >> 6, dd = idx & 63;
    int w = s_win[rr];
    float v;
    if (cbf != nullptr) v = round_bf16(cbf[(size_t)w * DIM + dd]);
    else                v = bfbits((uint32_t)((const uint16_t*)cb)[(size_t)w * DIM + dd]);
    out[base + idx] = v;
  }

  if (tid == 0) {
    double s = 0.0;
    for (int i = 0; i < ROWS_PER_BLOCK; ++i) s += s_loss[i];
    partials[blockIdx.x] = s;
  }
}

__global__ __launch_bounds__(256) void vq_loss_kernel(
    const double* __restrict__ partials, float* __restrict__ out) {
  __shared__ double sh[256];
  const int tid = threadIdx.x;
  double s = 0.0;
  for (int i = tid; i < NBLOCKS; i += 256) s += partials[i];
  sh[tid] = s;
  __syncthreads();
  if (tid == 0) {
    double t = 0.0;
    for (int i = 0; i < 256; ++i) t += sh[i];
    out[N_ELEMS] = round_bf16((float)(1.25 * t / (double)N_ELEMS));
  }
}

extern "C" void kernel_launch(void* const* d_in, const int* in_sizes, int n_in,
                              void* d_out, int out_size, void* d_ws, size_t ws_size,
                              hipStream_t stream) {
  const void* z  = d_in[0];
  const void* cb = d_in[1];
  float* out = (float*)d_out;
  uint8_t* ws = (uint8_t*)d_ws;
  float* cc = (float*)ws;
  int* flags = (int*)(ws + 4096);
  double* partials = (double*)(ws + 8192);
  const int use_ws = (ws_size >= (size_t)WS_NEED) ? 1 : 0;
  float* cbf_ws = use_ws ? (float*)(ws + WS_CBF_OFF) : nullptr;

  vq_prep_kernel<<<K_CODES / 256, 256, 0, stream>>>(z, cb, cc, flags, cbf_ws);
  vq_kernel<<<NBLOCKS, 256, 0, stream>>>(z, cb, cbf_ws, use_ws, cc, flags, out, partials);
  vq_loss_kernel<<<1, 256, 0, stream>>>(partials, out);
}

// Round 8
// 309.365 us; speedup vs baseline: 1.2690x; 1.2690x over previous
//
#include <hip/hip_runtime.h>
#include <stdint.h>

// VectorQuantizer: z [32768,64], codebook [1024,64] (dtype sniffed bf16/f32).
// d_out FLOAT32: z_q_st [2097152] ++ loss [1] ++ indices [32768].
// Bit-exact replication of the reference f32 arithmetic (numpy pairwise sums,
// sequential non-fused dot, f32 final adds, first-index argmin).
//
// R11 = R8 (262us, best verified) + ONE change: __launch_bounds__(256,1) on
// vq_kernel. Model fitted across R3/R8/R10: wall ~= loads_per_wave x ~600cy
// regardless of VALU count / wave count / bytes -> compiler sinks each 16B
// load to just-before-use (proved on R9: it deleted the hand pipeline; VGPR
// stayed 80), serializing load->wait->use. (256,1) licenses the allocator to
// exceed the ~80-VGPR occupancy target so it can batch loads in flight with
// counted vmcnt (the m131-140 behavior). TLP->ILP trade; R3-vs-R8 showed
// occupancy is nearly worthless here.
#define N_ROWS 32768
#define DIM 64
#define K_CODES 1024
#define ROWS_PER_BLOCK 32
#define PARTS 8
#define NGROUPS (K_CODES / (PARTS * 4))       // 32 groups of 4 codes per part
#define NBLOCKS (N_ROWS / ROWS_PER_BLOCK)     // 1024
#define N_ELEMS (N_ROWS * DIM)                // 2097152

// workspace layout (bytes):
// [0,4096)      float cc[1024]
// [4096,4100)   int flags  (bit0: z is bf16, bit1: cb is bf16)
// [8192,8192+NBLOCKS*8)  double partials[NBLOCKS]

__device__ __forceinline__ float bfbits(uint32_t b) { return __uint_as_float(b << 16); }
__device__ __forceinline__ float bf_lo(uint32_t u) { return __uint_as_float(u << 16); }
__device__ __forceinline__ float bf_hi(uint32_t u) { return __uint_as_float(u & 0xFFFF0000u); }

// round f32 -> nearest bf16 value, returned AS f32 (RNE; finite inputs)
__device__ __forceinline__ float round_bf16(float f) {
  uint32_t u = __float_as_uint(f);
  uint32_t r = ((u + 0x7FFFu + ((u >> 16) & 1u)) >> 16) << 16;
  return __uint_as_float(r);
}

// numpy pairwise_sum for n=64 (8 accumulators, 8 rounds, numpy's combine tree).
template <typename F>
__device__ __forceinline__ float np_sum64(F get) {
  float r0 = get(0), r1 = get(1), r2 = get(2), r3 = get(3);
  float r4 = get(4), r5 = get(5), r6 = get(6), r7 = get(7);
  for (int i = 8; i < 64; i += 8) {
    r0 = __fadd_rn(r0, get(i + 0)); r1 = __fadd_rn(r1, get(i + 1));
    r2 = __fadd_rn(r2, get(i + 2)); r3 = __fadd_rn(r3, get(i + 3));
    r4 = __fadd_rn(r4, get(i + 4)); r5 = __fadd_rn(r5, get(i + 5));
    r6 = __fadd_rn(r6, get(i + 6)); r7 = __fadd_rn(r7, get(i + 7));
  }
  return __fadd_rn(__fadd_rn(__fadd_rn(r0, r1), __fadd_rn(r2, r3)),
                   __fadd_rn(__fadd_rn(r4, r5), __fadd_rn(r6, r7)));
}

// Precompute: dtype sniff (block 0 writes flags) + cc_k = np.sum(c*c) per code.
__global__ __launch_bounds__(256) void vq_prep_kernel(
    const void* __restrict__ z, const void* __restrict__ cb,
    float* __restrict__ cc_out, int* __restrict__ flags) {
  const int tid = threadIdx.x;
  __shared__ int s_cnt[2];
  if (tid < 2) s_cnt[tid] = 0;
  __syncthreads();
  if (tid < 128) {
    uint32_t wc = ((const uint32_t*)cb)[(size_t)tid * 255];
    float vc = fabsf(bfbits(wc & 0xFFFFu));
    if (vc == 0.0f || (vc > 5.9e-8f && vc < 32.0f)) atomicAdd(&s_cnt[1], 1);
    if (blockIdx.x == 0) {
      uint32_t wz = ((const uint32_t*)z)[(size_t)tid * 8191];
      float vz = fabsf(bfbits(wz & 0xFFFFu));
      if (vz == 0.0f || (vz > 5.9e-8f && vz < 32.0f)) atomicAdd(&s_cnt[0], 1);
    }
  }
  __syncthreads();
  const bool cb_bf16 = s_cnt[1] >= 96;
  if (blockIdx.x == 0 && tid == 0)
    flags[0] = (s_cnt[0] >= 96 ? 1 : 0) | (cb_bf16 ? 2 : 0);

  const int kk = blockIdx.x * 256 + tid;
  float v;
  if (cb_bf16) {
    const uint16_t* cp = (const uint16_t*)cb + (size_t)kk * DIM;
    v = np_sum64([&](int d) { float c = bfbits((uint32_t)cp[d]);
                              return __fmul_rn(c, c); });
  } else {
    const float* cp = (const float*)cb + (size_t)kk * DIM;
    v = np_sum64([&](int d) { return __fmul_rn(cp[d], cp[d]); });
  }
  cc_out[kk] = v;
}

// Thread = (row r = tid&31, part = tid>>5); part p scans codes 32g+4p..+4 for
// g = 0..31 (ascending k within thread), 4-way ILP, vectorized global loads.
__global__ __launch_bounds__(256, 1) void vq_kernel(
    const void* __restrict__ z, const void* __restrict__ cb,
    const float* __restrict__ cc_in, const int* __restrict__ flags,
    float* __restrict__ out, double* __restrict__ partials) {
  const int tid = threadIdx.x;
  const int fl = flags[0];
  const bool z_bf16  = (fl & 1) != 0;
  const bool cb_bf16 = (fl & 2) != 0;

  __shared__ float s_cc[K_CODES];                 // 4 KB
  __shared__ float s_best[256];
  __shared__ int s_k[256];
  __shared__ int s_win[ROWS_PER_BLOCK];
  __shared__ double s_loss[ROWS_PER_BLOCK];

  #pragma unroll
  for (int kk = tid; kk < K_CODES; kk += 256) s_cc[kk] = cc_in[kk];

  const int r = tid & (ROWS_PER_BLOCK - 1);
  const int part = tid >> 5;
  const size_t row = (size_t)blockIdx.x * ROWS_PER_BLOCK + r;

  // Load z row as exact f32 values (vectorized).
  float zf[DIM];
  if (z_bf16) {
    const uint4* p = (const uint4*)((const uint16_t*)z + row * DIM);
    #pragma unroll
    for (int j = 0; j < 8; ++j) {
      uint4 u = p[j];
      zf[j * 8 + 0] = bf_lo(u.x); zf[j * 8 + 1] = bf_hi(u.x);
      zf[j * 8 + 2] = bf_lo(u.y); zf[j * 8 + 3] = bf_hi(u.y);
      zf[j * 8 + 4] = bf_lo(u.z); zf[j * 8 + 5] = bf_hi(u.z);
      zf[j * 8 + 6] = bf_lo(u.w); zf[j * 8 + 7] = bf_hi(u.w);
    }
  } else {
    const float4* p = (const float4*)((const float*)z + row * DIM);
    #pragma unroll
    for (int j = 0; j < 16; ++j) {
      float4 v = p[j];
      zf[j * 4 + 0] = v.x; zf[j * 4 + 1] = v.y;
      zf[j * 4 + 2] = v.z; zf[j * 4 + 3] = v.w;
    }
  }
  // zz = np.sum(z*z, axis=1) in f32, numpy pairwise order.
  const float zz = np_sum64([&](int d) { return __fmul_rn(zf[d], zf[d]); });

  __syncthreads();  // s_cc ready

  // Scan: d2 = fl(fl(zz + cc_k) - fl(2*g)), g = sequential f32 dot ascending d
  // (einsum inner loop, non-fused). Per-thread k ascending, strict < (np ties).
  float best = 3.4e38f;
  int bk = 0;
  if (cb_bf16) {
    for (int gi = 0; gi < NGROUPS; ++gi) {
      const int k = gi * 32 + part * 4;
      const uint4* c0 = (const uint4*)((const uint16_t*)cb + (size_t)(k + 0) * DIM);
      const uint4* c1 = (const uint4*)((const uint16_t*)cb + (size_t)(k + 1) * DIM);
      const uint4* c2 = (const uint4*)((const uint16_t*)cb + (size_t)(k + 2) * DIM);
      const uint4* c3 = (const uint4*)((const uint16_t*)cb + (size_t)(k + 3) * DIM);
      float g0 = 0.0f, g1 = 0.0f, g2 = 0.0f, g3 = 0.0f;
      #pragma unroll
      for (int j = 0; j < 8; ++j) {
        uint4 u0 = c0[j], u1 = c1[j], u2 = c2[j], u3 = c3[j];
        const int d0 = j * 8;
        g0 = __fadd_rn(g0, __fmul_rn(zf[d0 + 0], bf_lo(u0.x)));
        g0 = __fadd_rn(g0, __fmul_rn(zf[d0 + 1], bf_hi(u0.x)));
        g0 = __fadd_rn(g0, __fmul_rn(zf[d0 + 2], bf_lo(u0.y)));
        g0 = __fadd_rn(g0, __fmul_rn(zf[d0 + 3], bf_hi(u0.y)));
        g0 = __fadd_rn(g0, __fmul_rn(zf[d0 + 4], bf_lo(u0.z)));
        g0 = __fadd_rn(g0, __fmul_rn(zf[d0 + 5], bf_hi(u0.z)));
        g0 = __fadd_rn(g0, __fmul_rn(zf[d0 + 6], bf_lo(u0.w)));
        g0 = __fadd_rn(g0, __fmul_rn(zf[d0 + 7], bf_hi(u0.w)));
        g1 = __fadd_rn(g1, __fmul_rn(zf[d0 + 0], bf_lo(u1.x)));
        g1 = __fadd_rn(g1, __fmul_rn(zf[d0 + 1], bf_hi(u1.x)));
        g1 = __fadd_rn(g1, __fmul_rn(zf[d0 + 2], bf_lo(u1.y)));
        g1 = __fadd_rn(g1, __fmul_rn(zf[d0 + 3], bf_hi(u1.y)));
        g1 = __fadd_rn(g1, __fmul_rn(zf[d0 + 4], bf_lo(u1.z)));
        g1 = __fadd_rn(g1, __fmul_rn(zf[d0 + 5], bf_hi(u1.z)));
        g1 = __fadd_rn(g1, __fmul_rn(zf[d0 + 6], bf_lo(u1.w)));
        g1 = __fadd_rn(g1, __fmul_rn(zf[d0 + 7], bf_hi(u1.w)));
        g2 = __fadd_rn(g2, __fmul_rn(zf[d0 + 0], bf_lo(u2.x)));
        g2 = __fadd_rn(g2, __fmul_rn(zf[d0 + 1], bf_hi(u2.x)));
        g2 = __fadd_rn(g2, __fmul_rn(zf[d0 + 2], bf_lo(u2.y)));
        g2 = __fadd_rn(g2, __fmul_rn(zf[d0 + 3], bf_hi(u2.y)));
        g2 = __fadd_rn(g2, __fmul_rn(zf[d0 + 4], bf_lo(u2.z)));
        g2 = __fadd_rn(g2, __fmul_rn(zf[d0 + 5], bf_hi(u2.z)));
        g2 = __fadd_rn(g2, __fmul_rn(zf[d0 + 6], bf_lo(u2.w)));
        g2 = __fadd_rn(g2, __fmul_rn(zf[d0 + 7], bf_hi(u2.w)));
        g3 = __fadd_rn(g3, __fmul_rn(zf[d0 + 0], bf_lo(u3.x)));
        g3 = __fadd_rn(g3, __fmul_rn(zf[d0 + 1], bf_hi(u3.x)));
        g3 = __fadd_rn(g3, __fmul_rn(zf[d0 + 2], bf_lo(u3.y)));
        g3 = __fadd_rn(g3, __fmul_rn(zf[d0 + 3], bf_hi(u3.y)));
        g3 = __fadd_rn(g3, __fmul_rn(zf[d0 + 4], bf_lo(u3.z)));
        g3 = __fadd_rn(g3, __fmul_rn(zf[d0 + 5], bf_hi(u3.z)));
        g3 = __fadd_rn(g3, __fmul_rn(zf[d0 + 6], bf_lo(u3.w)));
        g3 = __fadd_rn(g3, __fmul_rn(zf[d0 + 7], bf_hi(u3.w)));
      }
      float e0 = __fsub_rn(__fadd_rn(zz, s_cc[k + 0]), __fmul_rn(2.0f, g0));
      float e1 = __fsub_rn(__fadd_rn(zz, s_cc[k + 1]), __fmul_rn(2.0f, g1));
      float e2 = __fsub_rn(__fadd_rn(zz, s_cc[k + 2]), __fmul_rn(2.0f, g2));
      float e3 = __fsub_rn(__fadd_rn(zz, s_cc[k + 3]), __fmul_rn(2.0f, g3));
      if (e0 < best) { best = e0; bk = k + 0; }
      if (e1 < best) { best = e1; bk = k + 1; }
      if (e2 < best) { best = e2; bk = k + 2; }
      if (e3 < best) { best = e3; bk = k + 3; }
    }
  } else {
    for (int gi = 0; gi < NGROUPS; ++gi) {
      const int k = gi * 32 + part * 4;
      const float4* c0 = (const float4*)((const float*)cb + (size_t)(k + 0) * DIM);
      const float4* c1 = (const float4*)((const float*)cb + (size_t)(k + 1) * DIM);
      const float4* c2 = (const float4*)((const float*)cb + (size_t)(k + 2) * DIM);
      const float4* c3 = (const float4*)((const float*)cb + (size_t)(k + 3) * DIM);
      float g0 = 0.0f, g1 = 0.0f, g2 = 0.0f, g3 = 0.0f;
      #pragma unroll
      for (int j = 0; j < 16; ++j) {
        float4 a = c0[j], b = c1[j], cc2 = c2[j], dd = c3[j];
        const int d0 = j * 4;
        g0 = __fadd_rn(g0, __fmul_rn(zf[d0 + 0], a.x));
        g0 = __fadd_rn(g0, __fmul_rn(zf[d0 + 1], a.y));
        g0 = __fadd_rn(g0, __fmul_rn(zf[d0 + 2], a.z));
        g0 = __fadd_rn(g0, __fmul_rn(zf[d0 + 3], a.w));
        g1 = __fadd_rn(g1, __fmul_rn(zf[d0 + 0], b.x));
        g1 = __fadd_rn(g1, __fmul_rn(zf[d0 + 1], b.y));
        g1 = __fadd_rn(g1, __fmul_rn(zf[d0 + 2], b.z));
        g1 = __fadd_rn(g1, __fmul_rn(zf[d0 + 3], b.w));
        g2 = __fadd_rn(g2, __fmul_rn(zf[d0 + 0], cc2.x));
        g2 = __fadd_rn(g2, __fmul_rn(zf[d0 + 1], cc2.y));
        g2 = __fadd_rn(g2, __fmul_rn(zf[d0 + 2], cc2.z));
        g2 = __fadd_rn(g2, __fmul_rn(zf[d0 + 3], cc2.w));
        g3 = __fadd_rn(g3, __fmul_rn(zf[d0 + 0], dd.x));
        g3 = __fadd_rn(g3, __fmul_rn(zf[d0 + 1], dd.y));
        g3 = __fadd_rn(g3, __fmul_rn(zf[d0 + 2], dd.z));
        g3 = __fadd_rn(g3, __fmul_rn(zf[d0 + 3], dd.w));
      }
      float e0 = __fsub_rn(__fadd_rn(zz, s_cc[k + 0]), __fmul_rn(2.0f, g0));
      float e1 = __fsub_rn(__fadd_rn(zz, s_cc[k + 1]), __fmul_rn(2.0f, g1));
      float e2 = __fsub_rn(__fadd_rn(zz, s_cc[k + 2]), __fmul_rn(2.0f, g2));
      float e3 = __fsub_rn(__fadd_rn(zz, s_cc[k + 3]), __fmul_rn(2.0f, g3));
      if (e0 < best) { best = e0; bk = k + 0; }
      if (e1 < best) { best = e1; bk = k + 1; }
      if (e2 < best) { best = e2; bk = k + 2; }
      if (e3 < best) { best = e3; bk = k + 3; }
    }
  }

  s_best[tid] = best;
  s_k[tid] = bk;
  __syncthreads();

  if (tid < ROWS_PER_BLOCK) {
    // Parts interleave k -> merge with lexicographic (d2, k): exactly the
    // global first-index (numpy) argmin.
    float b = 3.4e38f;
    int bbk = 0x7FFFFFFF;
    for (int p = 0; p < PARTS; ++p) {
      float v = s_best[p * ROWS_PER_BLOCK + tid];
      int vk = s_k[p * ROWS_PER_BLOCK + tid];
      if (v < b || (v == b && vk < bbk)) { b = v; bbk = vk; }
    }
    s_win[tid] = bbk;
    // Exact squared distance of the winner (fp64) — thread tid owns row tid's zf
    // (tid < 32 => r == tid, part == 0).
    double acc = 0.0;
    if (cb_bf16) {
      const uint16_t* cp = (const uint16_t*)cb + (size_t)bbk * DIM;
      for (int d = 0; d < DIM; ++d) {
        double df = (double)zf[d] - (double)bfbits((uint32_t)cp[d]);
        acc = fma(df, df, acc);
      }
    } else {
      const float* cp = (const float*)cb + (size_t)bbk * DIM;
      for (int d = 0; d < DIM; ++d) {
        double df = (double)zf[d] - (double)cp[d];
        acc = fma(df, df, acc);
      }
    }
    s_loss[tid] = acc;
    const size_t myrow = (size_t)blockIdx.x * ROWS_PER_BLOCK + tid;
    out[(size_t)N_ELEMS + 1 + myrow] = round_bf16((float)bbk);
  }
  __syncthreads();

  // z_q write: 32 rows x 64 dims = 2048 floats, 256 threads x 8, coalesced.
  const size_t base = (size_t)blockIdx.x * ROWS_PER_BLOCK * DIM;
  #pragma unroll
  for (int j = 0; j < 8; ++j) {
    int idx = tid + 256 * j;
    int rr = idx >> 6, dd = idx & 63;
    int w = s_win[rr];
    float v;
    if (cb_bf16) v = bfbits((uint32_t)((const uint16_t*)cb)[(size_t)w * DIM + dd]);
    else         v = round_bf16(((const float*)cb)[(size_t)w * DIM + dd]);
    out[base + idx] = v;
  }

  if (tid == 0) {
    double s = 0.0;
    for (int i = 0; i < ROWS_PER_BLOCK; ++i) s += s_loss[i];
    partials[blockIdx.x] = s;
  }
}

__global__ __launch_bounds__(256) void vq_loss_kernel(
    const double* __restrict__ partials, float* __restrict__ out) {
  __shared__ double sh[256];
  const int tid = threadIdx.x;
  double s = 0.0;
  for (int i = tid; i < NBLOCKS; i += 256) s += partials[i];
  sh[tid] = s;
  __syncthreads();
  if (tid == 0) {
    double t = 0.0;
    for (int i = 0; i < 256; ++i) t += sh[i];
    out[N_ELEMS] = round_bf16((float)(1.25 * t / (double)N_ELEMS));
  }
}

extern "C" void kernel_launch(void* const* d_in, const int* in_sizes, int n_in,
                              void* d_out, int out_size, void* d_ws, size_t ws_size,
                              hipStream_t stream) {
  const void* z  = d_in[0];
  const void* cb = d_in[1];
  float* out = (float*)d_out;
  uint8_t* ws = (uint8_t*)d_ws;
  float* cc = (float*)ws;
  int* flags = (int*)(ws + 4096);
  double* partials = (double*)(ws + 8192);

  vq_prep_kernel<<<K_CODES / 256, 256, 0, stream>>>(z, cb, cc, flags);
  vq_kernel<<<NBLOCKS, 256, 0, stream>>>(z, cb, cc, flags, out, partials);
  vq_loss_kernel<<<1, 256, 0, stream>>>(partials, out);
}

// Round 9
// 182.958 us; speedup vs baseline: 2.1458x; 1.6909x over previous
//
#include <hip/hip_runtime.h>
#include <stdint.h>

// VectorQuantizer: z [32768,64], codebook [1024,64] (dtype sniffed bf16/f32).
// d_out FLOAT32: z_q_st [2097152] ++ loss [1] ++ indices [32768].
// Bit-exact replication of the reference f32 arithmetic (numpy pairwise sums,
// sequential non-fused dot, f32 final adds, first-index argmin).
//
// R12 vs R3..R11: every round was bound by the per-wave serial VECTOR-load
// chain (~600cy/load exposed; compiler provably refuses to batch: R9 deleted
// a hand pipeline, R11's (256,1) left VGPR at 80). Codebook data is
// WAVE-UNIFORM -> move it to the scalar pipe: wave = 64 rows (lane=row),
// part = wave (8 waves/block of 512, contiguous 128-code ranges), codes
// s_load'ed into SGPRs from the f32 image (R10-verified prep), v_mul v,s,v.
// Zero vector loads in the hot loop. Contiguous parts merged ascending with
// strict < = global first-index (R3/R5-verified).
#define N_ROWS 32768
#define DIM 64
#define K_CODES 1024
#define ROWS_PER_BLOCK 64
#define PARTS 8
#define THREADS (ROWS_PER_BLOCK * PARTS)      // 512
#define CODES_PER_PART (K_CODES / PARTS)      // 128
#define NBLOCKS (N_ROWS / ROWS_PER_BLOCK)     // 512
#define N_ELEMS (N_ROWS * DIM)                // 2097152

// workspace layout (bytes):
// [0,4096)        float cc[1024]
// [4096,4100)     int flags  (bit0: z is bf16, bit1: cb is bf16)
// [8192,12288)    double partials[NBLOCKS=512]
// [24576,286720)  float cbf32[1024*64]  (only if ws_size >= 286720)
#define WS_CBF_OFF 24576
#define WS_NEED (WS_CBF_OFF + K_CODES * DIM * 4)

__device__ __forceinline__ float bfbits(uint32_t b) { return __uint_as_float(b << 16); }
__device__ __forceinline__ float bf_lo(uint32_t u) { return __uint_as_float(u << 16); }
__device__ __forceinline__ float bf_hi(uint32_t u) { return __uint_as_float(u & 0xFFFF0000u); }

// round f32 -> nearest bf16 value, returned AS f32 (RNE; finite inputs).
// Idempotent on values already on the bf16 grid.
__device__ __forceinline__ float round_bf16(float f) {
  uint32_t u = __float_as_uint(f);
  uint32_t r = ((u + 0x7FFFu + ((u >> 16) & 1u)) >> 16) << 16;
  return __uint_as_float(r);
}

// numpy pairwise_sum for n=64 (8 accumulators, 8 rounds, numpy's combine tree).
template <typename F>
__device__ __forceinline__ float np_sum64(F get) {
  float r0 = get(0), r1 = get(1), r2 = get(2), r3 = get(3);
  float r4 = get(4), r5 = get(5), r6 = get(6), r7 = get(7);
  for (int i = 8; i < 64; i += 8) {
    r0 = __fadd_rn(r0, get(i + 0)); r1 = __fadd_rn(r1, get(i + 1));
    r2 = __fadd_rn(r2, get(i + 2)); r3 = __fadd_rn(r3, get(i + 3));
    r4 = __fadd_rn(r4, get(i + 4)); r5 = __fadd_rn(r5, get(i + 5));
    r6 = __fadd_rn(r6, get(i + 6)); r7 = __fadd_rn(r7, get(i + 7));
  }
  return __fadd_rn(__fadd_rn(__fadd_rn(r0, r1), __fadd_rn(r2, r3)),
                   __fadd_rn(__fadd_rn(r4, r5), __fadd_rn(r6, r7)));
}

// Precompute (verified in R10): dtype sniff + cc_k = np.sum(c*c) per code +
// optional bf16->f32 codebook image.
__global__ __launch_bounds__(256) void vq_prep_kernel(
    const void* __restrict__ z, const void* __restrict__ cb,
    float* __restrict__ cc_out, int* __restrict__ flags,
    float* __restrict__ cbf_out) {
  const int tid = threadIdx.x;
  __shared__ int s_cnt[2];
  if (tid < 2) s_cnt[tid] = 0;
  __syncthreads();
  if (tid < 128) {
    uint32_t wc = ((const uint32_t*)cb)[(size_t)tid * 255];
    float vc = fabsf(bfbits(wc & 0xFFFFu));
    if (vc == 0.0f || (vc > 5.9e-8f && vc < 32.0f)) atomicAdd(&s_cnt[1], 1);
    if (blockIdx.x == 0) {
      uint32_t wz = ((const uint32_t*)z)[(size_t)tid * 8191];
      float vz = fabsf(bfbits(wz & 0xFFFFu));
      if (vz == 0.0f || (vz > 5.9e-8f && vz < 32.0f)) atomicAdd(&s_cnt[0], 1);
    }
  }
  __syncthreads();
  const bool cb_bf16 = s_cnt[1] >= 96;
  if (blockIdx.x == 0 && tid == 0)
    flags[0] = (s_cnt[0] >= 96 ? 1 : 0) | (cb_bf16 ? 2 : 0);

  const int kk = blockIdx.x * 256 + tid;
  float v;
  if (cb_bf16) {
    const uint16_t* cp = (const uint16_t*)cb + (size_t)kk * DIM;
    v = np_sum64([&](int d) { float c = bfbits((uint32_t)cp[d]);
                              return __fmul_rn(c, c); });
  } else {
    const float* cp = (const float*)cb + (size_t)kk * DIM;
    v = np_sum64([&](int d) { return __fmul_rn(cp[d], cp[d]); });
  }
  cc_out[kk] = v;

  // bf16 -> f32 codebook image (exact values).
  if (cb_bf16 && cbf_out != nullptr) {
    const uint4* src = (const uint4*)cb;
    float4* dst = (float4*)cbf_out;
    #pragma unroll
    for (int j = 0; j < 8; ++j) {
      int idx = blockIdx.x * 2048 + tid + 256 * j;
      uint4 u = src[idx];
      float4 lo, hi;
      lo.x = bf_lo(u.x); lo.y = bf_hi(u.x);
      lo.z = bf_lo(u.y); lo.w = bf_hi(u.y);
      hi.x = bf_lo(u.z); hi.y = bf_hi(u.z);
      hi.z = bf_lo(u.w); hi.w = bf_hi(u.w);
      dst[idx * 2] = lo;
      dst[idx * 2 + 1] = hi;
    }
  }
}

// Thread = (row r = tid&63, part = wave = tid>>6). Part p scans contiguous
// codes [p*128, (p+1)*128) ascending; code data is wave-uniform -> scalar.
__global__ __launch_bounds__(THREADS) void vq_kernel(
    const void* __restrict__ z, const void* __restrict__ cb,
    const float* __restrict__ cbf_ws, const int use_ws,
    const float* __restrict__ cc_in, const int* __restrict__ flags,
    float* __restrict__ out, double* __restrict__ partials) {
  const int tid = threadIdx.x;
  const int fl = flags[0];
  const bool z_bf16  = (fl & 1) != 0;
  const bool cb_bf16 = (fl & 2) != 0;
  // f32 image of the codebook (exact input values), when available.
  const float* cbf = !cb_bf16 ? (const float*)cb : (use_ws ? cbf_ws : nullptr);

  __shared__ float s_best[THREADS];
  __shared__ int s_k[THREADS];
  __shared__ int s_win[ROWS_PER_BLOCK];
  __shared__ double s_loss[ROWS_PER_BLOCK];

  const int r = tid & (ROWS_PER_BLOCK - 1);
  const int part = tid >> 6;                 // == wave id
  const size_t row = (size_t)blockIdx.x * ROWS_PER_BLOCK + r;

  // Load z row as exact f32 values (vectorized).
  float zf[DIM];
  if (z_bf16) {
    const uint4* p = (const uint4*)((const uint16_t*)z + row * DIM);
    #pragma unroll
    for (int j = 0; j < 8; ++j) {
      uint4 u = p[j];
      zf[j * 8 + 0] = bf_lo(u.x); zf[j * 8 + 1] = bf_hi(u.x);
      zf[j * 8 + 2] = bf_lo(u.y); zf[j * 8 + 3] = bf_hi(u.y);
      zf[j * 8 + 4] = bf_lo(u.z); zf[j * 8 + 5] = bf_hi(u.z);
      zf[j * 8 + 6] = bf_lo(u.w); zf[j * 8 + 7] = bf_hi(u.w);
    }
  } else {
    const float4* p = (const float4*)((const float*)z + row * DIM);
    #pragma unroll
    for (int j = 0; j < 16; ++j) {
      float4 v = p[j];
      zf[j * 4 + 0] = v.x; zf[j * 4 + 1] = v.y;
      zf[j * 4 + 2] = v.z; zf[j * 4 + 3] = v.w;
    }
  }
  // zz = np.sum(z*z, axis=1) in f32, numpy pairwise order.
  const float zz = np_sum64([&](int d) { return __fmul_rn(zf[d], zf[d]); });

  // Scan: d2 = fl(fl(zz + cc_k) - fl(2*g)), g = sequential f32 dot ascending d
  // (einsum inner loop, non-fused). Per-thread k ascending, strict < (np ties).
  float best = 3.4e38f;
  int bk = 0;

  if (cbf != nullptr) {
    // Wave-uniform code pointer -> scalar loads (s_load), broadcast to lanes.
    const int part_u = __builtin_amdgcn_readfirstlane(part);
    const float* cp_base = cbf + (size_t)part_u * CODES_PER_PART * DIM;
    const float* cc_base = cc_in + part_u * CODES_PER_PART;
    const int k0 = part_u * CODES_PER_PART;
    for (int i = 0; i < CODES_PER_PART; ++i) {
      // Uniform loads: compiler emits s_load bursts into SGPRs.
      float cs[DIM];
      #pragma unroll
      for (int d = 0; d < DIM; ++d) cs[d] = cp_base[i * DIM + d];
      const float cck = cc_base[i];
      float g = 0.0f;
      #pragma unroll
      for (int d = 0; d < DIM; ++d)
        g = __fadd_rn(g, __fmul_rn(zf[d], cs[d]));
      float e = __fsub_rn(__fadd_rn(zz, cck), __fmul_rn(2.0f, g));
      const int k = k0 + i;
      if (e < best) { best = e; bk = k; }
    }
  } else {
    // bf16 fallback (cb bf16, workspace too small): per-lane vector loads.
    const uint4* cb4 = (const uint4*)cb;      // 8 uint4 per code
    const int k0 = part * CODES_PER_PART;
    for (int i = 0; i < CODES_PER_PART; ++i) {
      const int k = k0 + i;
      const uint4* c0 = cb4 + (size_t)k * 8;
      float g = 0.0f;
      #pragma unroll
      for (int j = 0; j < 8; ++j) {
        uint4 u = c0[j];
        const int d0 = j * 8;
        g = __fadd_rn(g, __fmul_rn(zf[d0 + 0], bf_lo(u.x)));
        g = __fadd_rn(g, __fmul_rn(zf[d0 + 1], bf_hi(u.x)));
        g = __fadd_rn(g, __fmul_rn(zf[d0 + 2], bf_lo(u.y)));
        g = __fadd_rn(g, __fmul_rn(zf[d0 + 3], bf_hi(u.y)));
        g = __fadd_rn(g, __fmul_rn(zf[d0 + 4], bf_lo(u.z)));
        g = __fadd_rn(g, __fmul_rn(zf[d0 + 5], bf_hi(u.z)));
        g = __fadd_rn(g, __fmul_rn(zf[d0 + 6], bf_lo(u.w)));
        g = __fadd_rn(g, __fmul_rn(zf[d0 + 7], bf_hi(u.w)));
      }
      float e = __fsub_rn(__fadd_rn(zz, cc_in[k]), __fmul_rn(2.0f, g));
      if (e < best) { best = e; bk = k; }
    }
  }

  s_best[tid] = best;
  s_k[tid] = bk;
  __syncthreads();

  if (tid < ROWS_PER_BLOCK) {
    // Contiguous parts, ascending, strict < -> global first-index argmin.
    float b = s_best[tid];
    int bbk = s_k[tid];
    for (int p = 1; p < PARTS; ++p) {
      float v = s_best[p * ROWS_PER_BLOCK + tid];
      if (v < b) { b = v; bbk = s_k[p * ROWS_PER_BLOCK + tid]; }
    }
    s_win[tid] = bbk;
    // Exact squared distance of the winner (fp64) — thread tid owns row tid's
    // zf (tid < 64 => r == tid, part == 0).
    double acc = 0.0;
    if (cbf != nullptr) {
      const float* cp = cbf + (size_t)bbk * DIM;
      for (int d = 0; d < DIM; ++d) {
        double df = (double)zf[d] - (double)cp[d];
        acc = fma(df, df, acc);
      }
    } else {
      const uint16_t* cp = (const uint16_t*)cb + (size_t)bbk * DIM;
      for (int d = 0; d < DIM; ++d) {
        double df = (double)zf[d] - (double)bfbits((uint32_t)cp[d]);
        acc = fma(df, df, acc);
      }
    }
    s_loss[tid] = acc;
    const size_t myrow = (size_t)blockIdx.x * ROWS_PER_BLOCK + tid;
    out[(size_t)N_ELEMS + 1 + myrow] = round_bf16((float)bbk);
  }
  __syncthreads();

  // z_q write: 64 rows x 64 dims = 4096 floats, 512 threads x 8, coalesced.
  // round_bf16 is idempotent on bf16-grid values -> correct for both paths.
  const size_t base = (size_t)blockIdx.x * ROWS_PER_BLOCK * DIM;
  #pragma unroll
  for (int j = 0; j < 8; ++j) {
    int idx = tid + THREADS * j;
    int rr = idx >> 6, dd = idx & 63;
    int w = s_win[rr];
    float v;
    if (cbf != nullptr) v = round_bf16(cbf[(size_t)w * DIM + dd]);
    else                v = bfbits((uint32_t)((const uint16_t*)cb)[(size_t)w * DIM + dd]);
    out[base + idx] = v;
  }

  if (tid == 0) {
    double s = 0.0;
    for (int i = 0; i < ROWS_PER_BLOCK; ++i) s += s_loss[i];
    partials[blockIdx.x] = s;
  }
}

__global__ __launch_bounds__(256) void vq_loss_kernel(
    const double* __restrict__ partials, float* __restrict__ out) {
  __shared__ double sh[256];
  const int tid = threadIdx.x;
  double s = 0.0;
  for (int i = tid; i < NBLOCKS; i += 256) s += partials[i];
  sh[tid] = s;
  __syncthreads();
  if (tid == 0) {
    double t = 0.0;
    for (int i = 0; i < 256; ++i) t += sh[i];
    out[N_ELEMS] = round_bf16((float)(1.25 * t / (double)N_ELEMS));
  }
}

extern "C" void kernel_launch(void* const* d_in, const int* in_sizes, int n_in,
                              void* d_out, int out_size, void* d_ws, size_t ws_size,
                              hipStream_t stream) {
  const void* z  = d_in[0];
  const void* cb = d_in[1];
  float* out = (float*)d_out;
  uint8_t* ws = (uint8_t*)d_ws;
  float* cc = (float*)ws;
  int* flags = (int*)(ws + 4096);
  double* partials = (double*)(ws + 8192);
  const int use_ws = (ws_size >= (size_t)WS_NEED) ? 1 : 0;
  float* cbf_ws = use_ws ? (float*)(ws + WS_CBF_OFF) : nullptr;

  vq_prep_kernel<<<K_CODES / 256, 256, 0, stream>>>(z, cb, cc, flags, cbf_ws);
  vq_kernel<<<NBLOCKS, THREADS, 0, stream>>>(z, cb, cbf_ws, use_ws, cc, flags, out, partials);
  vq_loss_kernel<<<1, 256, 0, stream>>>(partials, out);
}

// Round 10
// 142.312 us; speedup vs baseline: 2.7587x; 1.2856x over previous
//
#include <hip/hip_runtime.h>
#include <stdint.h>

// VectorQuantizer: z [32768,64], codebook [1024,64] (dtype sniffed bf16/f32).
// d_out FLOAT32: z_q_st [2097152] ++ loss [1] ++ indices [32768].
// Bit-exact replication of the reference f32 arithmetic (numpy pairwise sums,
// sequential non-fused dot, f32 final adds, first-index argmin).
//
// R13 vs R12 (126us vq, VALUBusy 53.5%): R12's scalar path exposed ~8 SMEM
// drain latencies per code (SMEM is lgkmcnt(0)-only; 96 SGPRs can't hold a
// code + prefetch). Fix by REUSE, not pipe choice: GEMM-style tiling. Block =
// 64 rows x 1024 codes; z and each 128-code chunk staged TRANSPOSED in LDS
// (f32); thread owns 4 rows x 8 codes of accumulators; per d: 3 ds_read_b128
// feed 64 VALU ops (4x/8x reuse) -> VALU-bound. Per-(row,code) chain is the
// identical fadd(fmul) ascending-d sequence as all passing rounds; per-thread
// k ascending; cross-thread merge lexicographic (d2,k) (R8-verified).
#define N_ROWS 32768
#define DIM 64
#define K_CODES 1024
#define ROWS_PER_BLOCK 64
#define THREADS 256
#define CHUNK 128
#define NCHUNK (K_CODES / CHUNK)              // 8
#define NBLOCKS (N_ROWS / ROWS_PER_BLOCK)     // 512
#define N_ELEMS (N_ROWS * DIM)                // 2097152
#define ZT_STRIDE 68                          // 64+4 floats; 272B, 16B-aligned rows
#define CT_STRIDE 132                         // 128+4 floats; 528B, 16B-aligned rows

// workspace layout (bytes):
// [0,4096)      float cc[1024]
// [4096,4100)   int flags  (bit0: z is bf16, bit1: cb is bf16)
// [8192,12288)  double partials[NBLOCKS=512]

__device__ __forceinline__ float bfbits(uint32_t b) { return __uint_as_float(b << 16); }
__device__ __forceinline__ float bf_lo(uint32_t u) { return __uint_as_float(u << 16); }
__device__ __forceinline__ float bf_hi(uint32_t u) { return __uint_as_float(u & 0xFFFF0000u); }

// round f32 -> nearest bf16 value, returned AS f32 (RNE; finite inputs).
__device__ __forceinline__ float round_bf16(float f) {
  uint32_t u = __float_as_uint(f);
  uint32_t r = ((u + 0x7FFFu + ((u >> 16) & 1u)) >> 16) << 16;
  return __uint_as_float(r);
}

// numpy pairwise_sum for n=64 (8 accumulators, 8 rounds, numpy's combine tree).
template <typename F>
__device__ __forceinline__ float np_sum64(F get) {
  float r0 = get(0), r1 = get(1), r2 = get(2), r3 = get(3);
  float r4 = get(4), r5 = get(5), r6 = get(6), r7 = get(7);
  for (int i = 8; i < 64; i += 8) {
    r0 = __fadd_rn(r0, get(i + 0)); r1 = __fadd_rn(r1, get(i + 1));
    r2 = __fadd_rn(r2, get(i + 2)); r3 = __fadd_rn(r3, get(i + 3));
    r4 = __fadd_rn(r4, get(i + 4)); r5 = __fadd_rn(r5, get(i + 5));
    r6 = __fadd_rn(r6, get(i + 6)); r7 = __fadd_rn(r7, get(i + 7));
  }
  return __fadd_rn(__fadd_rn(__fadd_rn(r0, r1), __fadd_rn(r2, r3)),
                   __fadd_rn(__fadd_rn(r4, r5), __fadd_rn(r6, r7)));
}

// Precompute: dtype sniff (block 0 writes flags) + cc_k = np.sum(c*c) per code.
// Vectorized loads (R12's scalar-chain prep cost ~20-30us of the total).
__global__ __launch_bounds__(256) void vq_prep_kernel(
    const void* __restrict__ z, const void* __restrict__ cb,
    float* __restrict__ cc_out, int* __restrict__ flags) {
  const int tid = threadIdx.x;
  __shared__ int s_cnt[2];
  if (tid < 2) s_cnt[tid] = 0;
  __syncthreads();
  if (tid < 128) {
    uint32_t wc = ((const uint32_t*)cb)[(size_t)tid * 255];
    float vc = fabsf(bfbits(wc & 0xFFFFu));
    if (vc == 0.0f || (vc > 5.9e-8f && vc < 32.0f)) atomicAdd(&s_cnt[1], 1);
    if (blockIdx.x == 0) {
      uint32_t wz = ((const uint32_t*)z)[(size_t)tid * 8191];
      float vz = fabsf(bfbits(wz & 0xFFFFu));
      if (vz == 0.0f || (vz > 5.9e-8f && vz < 32.0f)) atomicAdd(&s_cnt[0], 1);
    }
  }
  __syncthreads();
  const bool cb_bf16 = s_cnt[1] >= 96;
  if (blockIdx.x == 0 && tid == 0)
    flags[0] = (s_cnt[0] >= 96 ? 1 : 0) | (cb_bf16 ? 2 : 0);

  const int kk = blockIdx.x * 256 + tid;
  float cv[DIM];
  if (cb_bf16) {
    const uint4* cp = (const uint4*)((const uint16_t*)cb + (size_t)kk * DIM);
    #pragma unroll
    for (int j = 0; j < 8; ++j) {
      uint4 u = cp[j];
      cv[j * 8 + 0] = bf_lo(u.x); cv[j * 8 + 1] = bf_hi(u.x);
      cv[j * 8 + 2] = bf_lo(u.y); cv[j * 8 + 3] = bf_hi(u.y);
      cv[j * 8 + 4] = bf_lo(u.z); cv[j * 8 + 5] = bf_hi(u.z);
      cv[j * 8 + 6] = bf_lo(u.w); cv[j * 8 + 7] = bf_hi(u.w);
    }
  } else {
    const float4* cp = (const float4*)((const float*)cb + (size_t)kk * DIM);
    #pragma unroll
    for (int j = 0; j < 16; ++j) {
      float4 v = cp[j];
      cv[j * 4 + 0] = v.x; cv[j * 4 + 1] = v.y;
      cv[j * 4 + 2] = v.z; cv[j * 4 + 3] = v.w;
    }
  }
  cc_out[kk] = np_sum64([&](int d) { return __fmul_rn(cv[d], cv[d]); });
}

// Thread tile: TR = tid&15 (row group of 4), TK = tid>>4 (code group of 8).
__global__ __launch_bounds__(THREADS) void vq_kernel(
    const void* __restrict__ z, const void* __restrict__ cb,
    const float* __restrict__ cc_in, const int* __restrict__ flags,
    float* __restrict__ out, double* __restrict__ partials) {
  const int tid = threadIdx.x;
  const int fl = flags[0];
  const bool z_bf16  = (fl & 1) != 0;
  const bool cb_bf16 = (fl & 2) != 0;

  __shared__ float zt[DIM][ZT_STRIDE];          // zt[d][row], exact f32 z
  __shared__ float ct[DIM][CT_STRIDE];          // ct[d][kc], exact f32 codes
  __shared__ float s_cc[K_CODES];
  __shared__ float s_zz[ROWS_PER_BLOCK];
  __shared__ float s_bestM[16][ROWS_PER_BLOCK];
  __shared__ int   s_kM[16][ROWS_PER_BLOCK];
  __shared__ int   s_win[ROWS_PER_BLOCK];
  __shared__ double s_loss[ROWS_PER_BLOCK];

  const int TR = tid & 15;
  const int TK = tid >> 4;
  const size_t row0 = (size_t)blockIdx.x * ROWS_PER_BLOCK;

  // stage cc
  #pragma unroll
  for (int kk = tid; kk < K_CODES; kk += THREADS) s_cc[kk] = cc_in[kk];

  // stage z transposed (exact f32 values)
  if (z_bf16) {
    const uint4* src = (const uint4*)((const uint16_t*)z + row0 * DIM);
    #pragma unroll
    for (int j = 0; j < 2; ++j) {
      int idx = tid + THREADS * j;              // [0,512)
      int row = idx >> 3, d0 = (idx & 7) * 8;
      uint4 u = src[idx];
      zt[d0 + 0][row] = bf_lo(u.x); zt[d0 + 1][row] = bf_hi(u.x);
      zt[d0 + 2][row] = bf_lo(u.y); zt[d0 + 3][row] = bf_hi(u.y);
      zt[d0 + 4][row] = bf_lo(u.z); zt[d0 + 5][row] = bf_hi(u.z);
      zt[d0 + 6][row] = bf_lo(u.w); zt[d0 + 7][row] = bf_hi(u.w);
    }
  } else {
    const float4* src = (const float4*)((const float*)z + row0 * DIM);
    #pragma unroll
    for (int j = 0; j < 4; ++j) {
      int idx = tid + THREADS * j;              // [0,1024)
      int row = idx >> 4, d0 = (idx & 15) * 4;
      float4 v = src[idx];
      zt[d0 + 0][row] = v.x; zt[d0 + 1][row] = v.y;
      zt[d0 + 2][row] = v.z; zt[d0 + 3][row] = v.w;
    }
  }
  __syncthreads();

  // zz per row = np.sum(z*z) in f32, numpy pairwise order over products.
  if (tid < ROWS_PER_BLOCK) {
    const int r = tid;
    s_zz[r] = np_sum64([&](int d) { float v = zt[d][r]; return __fmul_rn(v, v); });
  }

  float best[4] = {3.4e38f, 3.4e38f, 3.4e38f, 3.4e38f};
  int bk[4] = {0, 0, 0, 0};
  float acc[4][8];
  #pragma unroll
  for (int ri = 0; ri < 4; ++ri)
    #pragma unroll
    for (int ki = 0; ki < 8; ++ki) acc[ri][ki] = 0.0f;

  for (int c = 0; c < NCHUNK; ++c) {
    __syncthreads();  // prev chunk compute done (c=0: zz done)
    // stage chunk c transposed (exact f32 values)
    if (cb_bf16) {
      const uint4* src = (const uint4*)((const uint16_t*)cb + (size_t)c * CHUNK * DIM);
      #pragma unroll
      for (int j = 0; j < 4; ++j) {
        int idx = tid + THREADS * j;            // [0,1024)
        int kc = idx >> 3, d0 = (idx & 7) * 8;
        uint4 u = src[idx];
        ct[d0 + 0][kc] = bf_lo(u.x); ct[d0 + 1][kc] = bf_hi(u.x);
        ct[d0 + 2][kc] = bf_lo(u.y); ct[d0 + 3][kc] = bf_hi(u.y);
        ct[d0 + 4][kc] = bf_lo(u.z); ct[d0 + 5][kc] = bf_hi(u.z);
        ct[d0 + 6][kc] = bf_lo(u.w); ct[d0 + 7][kc] = bf_hi(u.w);
      }
    } else {
      const float4* src = (const float4*)((const float*)cb + (size_t)c * CHUNK * DIM);
      #pragma unroll
      for (int j = 0; j < 8; ++j) {
        int idx = tid + THREADS * j;            // [0,2048)
        int kc = idx >> 4, d0 = (idx & 15) * 4;
        float4 v = src[idx];
        ct[d0 + 0][kc] = v.x; ct[d0 + 1][kc] = v.y;
        ct[d0 + 2][kc] = v.z; ct[d0 + 3][kc] = v.w;
      }
    }
    __syncthreads();

    // inner: per d, 3 ds_read_b128 -> 32 muls + 32 adds (non-fused, chain
    // per (row,code) ascending d == reference einsum order).
    #pragma unroll 4
    for (int d = 0; d < DIM; ++d) {
      float4 zv4 = *(const float4*)&zt[d][TR * 4];
      float4 ca  = *(const float4*)&ct[d][TK * 8];
      float4 cb2 = *(const float4*)&ct[d][TK * 8 + 4];
      float zv[4] = {zv4.x, zv4.y, zv4.z, zv4.w};
      float cv[8] = {ca.x, ca.y, ca.z, ca.w, cb2.x, cb2.y, cb2.z, cb2.w};
      #pragma unroll
      for (int ri = 0; ri < 4; ++ri)
        #pragma unroll
        for (int ki = 0; ki < 8; ++ki)
          acc[ri][ki] = __fadd_rn(acc[ri][ki], __fmul_rn(zv[ri], cv[ki]));
    }

    // epilogue: d2 = fl(fl(zz+cc) - fl(2*g)); per-thread k ascending, strict <.
    #pragma unroll
    for (int ri = 0; ri < 4; ++ri) {
      const float zzr = s_zz[TR * 4 + ri];
      #pragma unroll
      for (int ki = 0; ki < 8; ++ki) {
        const int k = c * CHUNK + TK * 8 + ki;
        float e = __fsub_rn(__fadd_rn(zzr, s_cc[k]), __fmul_rn(2.0f, acc[ri][ki]));
        if (e < best[ri]) { best[ri] = e; bk[ri] = k; }
        acc[ri][ki] = 0.0f;
      }
    }
  }

  #pragma unroll
  for (int ri = 0; ri < 4; ++ri) {
    s_bestM[TK][TR * 4 + ri] = best[ri];
    s_kM[TK][TR * 4 + ri] = bk[ri];
  }
  __syncthreads();

  if (tid < ROWS_PER_BLOCK) {
    // TK ranges interleave k -> lexicographic (d2,k) merge == global
    // first-index (numpy) argmin (R8-verified equivalence).
    float b = 3.4e38f;
    int bbk = 0x7FFFFFFF;
    for (int p = 0; p < 16; ++p) {
      float v = s_bestM[p][tid];
      int vk = s_kM[p][tid];
      if (v < b || (v == b && vk < bbk)) { b = v; bbk = vk; }
    }
    s_win[tid] = bbk;
    // Exact squared distance of the winner (fp64); exact z from zt column.
    double acc2 = 0.0;
    if (cb_bf16) {
      const uint16_t* cp = (const uint16_t*)cb + (size_t)bbk * DIM;
      for (int d = 0; d < DIM; ++d) {
        double df = (double)zt[d][tid] - (double)bfbits((uint32_t)cp[d]);
        acc2 = fma(df, df, acc2);
      }
    } else {
      const float* cp = (const float*)cb + (size_t)bbk * DIM;
      for (int d = 0; d < DIM; ++d) {
        double df = (double)zt[d][tid] - (double)cp[d];
        acc2 = fma(df, df, acc2);
      }
    }
    s_loss[tid] = acc2;
    out[(size_t)N_ELEMS + 1 + row0 + tid] = round_bf16((float)bbk);
  }
  __syncthreads();

  // z_q write: 64 rows x 64 dims = 4096 floats, 256 threads x 16, coalesced.
  const size_t base = row0 * DIM;
  #pragma unroll
  for (int j = 0; j < 16; ++j) {
    int idx = tid + THREADS * j;
    int rr = idx >> 6, dd = idx & 63;
    int w = s_win[rr];
    float v;
    if (cb_bf16) v = bfbits((uint32_t)((const uint16_t*)cb)[(size_t)w * DIM + dd]);
    else         v = round_bf16(((const float*)cb)[(size_t)w * DIM + dd]);
    out[base + idx] = v;
  }

  if (tid == 0) {
    double s = 0.0;
    for (int i = 0; i < ROWS_PER_BLOCK; ++i) s += s_loss[i];
    partials[blockIdx.x] = s;
  }
}

__global__ __launch_bounds__(256) void vq_loss_kernel(
    const double* __restrict__ partials, float* __restrict__ out) {
  __shared__ double sh[256];
  const int tid = threadIdx.x;
  double s = 0.0;
  for (int i = tid; i < NBLOCKS; i += 256) s += partials[i];
  sh[tid] = s;
  __syncthreads();
  if (tid == 0) {
    double t = 0.0;
    for (int i = 0; i < 256; ++i) t += sh[i];
    out[N_ELEMS] = round_bf16((float)(1.25 * t / (double)N_ELEMS));
  }
}

extern "C" void kernel_launch(void* const* d_in, const int* in_sizes, int n_in,
                              void* d_out, int out_size, void* d_ws, size_t ws_size,
                              hipStream_t stream) {
  const void* z  = d_in[0];
  const void* cb = d_in[1];
  float* out = (float*)d_out;
  uint8_t* ws = (uint8_t*)d_ws;
  float* cc = (float*)ws;
  int* flags = (int*)(ws + 4096);
  double* partials = (double*)(ws + 8192);

  vq_prep_kernel<<<K_CODES / 256, 256, 0, stream>>>(z, cb, cc, flags);
  vq_kernel<<<NBLOCKS, THREADS, 0, stream>>>(z, cb, cc, flags, out, partials);
  vq_loss_kernel<<<1, 256, 0, stream>>>(partials, out);
}

// Round 11
// 142.106 us; speedup vs baseline: 2.7627x; 1.0015x over previous
//
#include <hip/hip_runtime.h>
#include <stdint.h>

// VectorQuantizer: z [32768,64], codebook [1024,64] (dtype sniffed bf16/f32).
// d_out FLOAT32: z_q_st [2097152] ++ loss [1] ++ indices [32768].
// Bit-exact replication of the reference f32 arithmetic (numpy pairwise sums,
// sequential non-fused dot, f32 final adds, first-index argmin).
//
// R14 vs R13 (87.7us vq, VALUBusy 43%, LDS-read-pipe-bound at 21.3 ops/read):
// double the register tile to 8 rows x 8 codes (32 ops/read) -> VALU-bound.
// Block = 128 rows x 1024 codes, 512 threads, 4 chunks of 256 codes staged
// transposed in LDS. zt uses a split-plane layout so the two 8-row b128 reads
// stay 16B-contiguous across lanes (conflict-free). Wave-level lexicographic
// (d2,k) merge via shfl_xor keeps LDS at 110KB (128KB is gfx950-proven).
#define N_ROWS 32768
#define DIM 64
#define K_CODES 1024
#define ROWS_PER_BLOCK 128
#define THREADS 512
#define CHUNK 256
#define NCHUNK (K_CODES / CHUNK)              // 4
#define NBLOCKS (N_ROWS / ROWS_PER_BLOCK)     // 256
#define N_ELEMS (N_ROWS * DIM)                // 2097152
#define ZT_STRIDE 128
#define CT_STRIDE 256

// workspace layout (bytes):
// [0,4096)      float cc[1024]
// [4096,4100)   int flags  (bit0: z is bf16, bit1: cb is bf16)
// [8192,12288)  double partials[NBLOCKS<=512]

__device__ __forceinline__ float bfbits(uint32_t b) { return __uint_as_float(b << 16); }
__device__ __forceinline__ float bf_lo(uint32_t u) { return __uint_as_float(u << 16); }
__device__ __forceinline__ float bf_hi(uint32_t u) { return __uint_as_float(u & 0xFFFF0000u); }

// round f32 -> nearest bf16 value, returned AS f32 (RNE; finite inputs).
__device__ __forceinline__ float round_bf16(float f) {
  uint32_t u = __float_as_uint(f);
  uint32_t r = ((u + 0x7FFFu + ((u >> 16) & 1u)) >> 16) << 16;
  return __uint_as_float(r);
}

// zt split-plane column: row = 8*TR + s -> col = TR*4 + (s>>2)*64 + (s&3).
// Keeps each thread's rows 0..3 / 4..7 as 16B-contiguous, lane-contiguous.
__device__ __forceinline__ int zcol(int row) {
  return ((row >> 3) << 2) + (((row >> 2) & 1) << 6) + (row & 3);
}

// numpy pairwise_sum for n=64 (8 accumulators, 8 rounds, numpy's combine tree).
template <typename F>
__device__ __forceinline__ float np_sum64(F get) {
  float r0 = get(0), r1 = get(1), r2 = get(2), r3 = get(3);
  float r4 = get(4), r5 = get(5), r6 = get(6), r7 = get(7);
  for (int i = 8; i < 64; i += 8) {
    r0 = __fadd_rn(r0, get(i + 0)); r1 = __fadd_rn(r1, get(i + 1));
    r2 = __fadd_rn(r2, get(i + 2)); r3 = __fadd_rn(r3, get(i + 3));
    r4 = __fadd_rn(r4, get(i + 4)); r5 = __fadd_rn(r5, get(i + 5));
    r6 = __fadd_rn(r6, get(i + 6)); r7 = __fadd_rn(r7, get(i + 7));
  }
  return __fadd_rn(__fadd_rn(__fadd_rn(r0, r1), __fadd_rn(r2, r3)),
                   __fadd_rn(__fadd_rn(r4, r5), __fadd_rn(r6, r7)));
}

// Precompute (R13-verified): dtype sniff + cc_k = np.sum(c*c), vectorized.
__global__ __launch_bounds__(256) void vq_prep_kernel(
    const void* __restrict__ z, const void* __restrict__ cb,
    float* __restrict__ cc_out, int* __restrict__ flags) {
  const int tid = threadIdx.x;
  __shared__ int s_cnt[2];
  if (tid < 2) s_cnt[tid] = 0;
  __syncthreads();
  if (tid < 128) {
    uint32_t wc = ((const uint32_t*)cb)[(size_t)tid * 255];
    float vc = fabsf(bfbits(wc & 0xFFFFu));
    if (vc == 0.0f || (vc > 5.9e-8f && vc < 32.0f)) atomicAdd(&s_cnt[1], 1);
    if (blockIdx.x == 0) {
      uint32_t wz = ((const uint32_t*)z)[(size_t)tid * 8191];
      float vz = fabsf(bfbits(wz & 0xFFFFu));
      if (vz == 0.0f || (vz > 5.9e-8f && vz < 32.0f)) atomicAdd(&s_cnt[0], 1);
    }
  }
  __syncthreads();
  const bool cb_bf16 = s_cnt[1] >= 96;
  if (blockIdx.x == 0 && tid == 0)
    flags[0] = (s_cnt[0] >= 96 ? 1 : 0) | (cb_bf16 ? 2 : 0);

  const int kk = blockIdx.x * 256 + tid;
  float cv[DIM];
  if (cb_bf16) {
    const uint4* cp = (const uint4*)((const uint16_t*)cb + (size_t)kk * DIM);
    #pragma unroll
    for (int j = 0; j < 8; ++j) {
      uint4 u = cp[j];
      cv[j * 8 + 0] = bf_lo(u.x); cv[j * 8 + 1] = bf_hi(u.x);
      cv[j * 8 + 2] = bf_lo(u.y); cv[j * 8 + 3] = bf_hi(u.y);
      cv[j * 8 + 4] = bf_lo(u.z); cv[j * 8 + 5] = bf_hi(u.z);
      cv[j * 8 + 6] = bf_lo(u.w); cv[j * 8 + 7] = bf_hi(u.w);
    }
  } else {
    const float4* cp = (const float4*)((const float*)cb + (size_t)kk * DIM);
    #pragma unroll
    for (int j = 0; j < 16; ++j) {
      float4 v = cp[j];
      cv[j * 4 + 0] = v.x; cv[j * 4 + 1] = v.y;
      cv[j * 4 + 2] = v.z; cv[j * 4 + 3] = v.w;
    }
  }
  cc_out[kk] = np_sum64([&](int d) { return __fmul_rn(cv[d], cv[d]); });
}

// Thread tile: TR = tid&15 (8 rows), TK = tid>>4 in [0,32) (8 codes of 256).
__global__ __launch_bounds__(THREADS, 1) void vq_kernel(
    const void* __restrict__ z, const void* __restrict__ cb,
    const float* __restrict__ cc_in, const int* __restrict__ flags,
    float* __restrict__ out, double* __restrict__ partials) {
  const int tid = threadIdx.x;
  const int fl = flags[0];
  const bool z_bf16  = (fl & 1) != 0;
  const bool cb_bf16 = (fl & 2) != 0;

  __shared__ float zt[DIM][ZT_STRIDE];          // 32 KB, split-plane cols
  __shared__ float ct[DIM][CT_STRIDE];          // 64 KB
  __shared__ float s_cc[K_CODES];               // 4 KB
  __shared__ float s_zz[ROWS_PER_BLOCK];        // 512 B
  __shared__ float s_bestW[8][ROWS_PER_BLOCK];  // 4 KB (per-wave candidates)
  __shared__ int   s_kW[8][ROWS_PER_BLOCK];     // 4 KB
  __shared__ int   s_win[ROWS_PER_BLOCK];       // 512 B
  __shared__ double s_loss[ROWS_PER_BLOCK];     // 1 KB

  const int TR = tid & 15;
  const int TK = tid >> 4;
  const size_t row0 = (size_t)blockIdx.x * ROWS_PER_BLOCK;

  // stage cc
  #pragma unroll
  for (int kk = tid; kk < K_CODES; kk += THREADS) s_cc[kk] = cc_in[kk];

  // stage z transposed into split-plane layout (exact f32 values)
  if (z_bf16) {
    const uint4* src = (const uint4*)((const uint16_t*)z + row0 * DIM);
    #pragma unroll
    for (int j = 0; j < 2; ++j) {
      int idx = tid + THREADS * j;              // [0,1024)
      int row = idx >> 3, d0 = (idx & 7) * 8;
      int col = zcol(row);
      uint4 u = src[idx];
      zt[d0 + 0][col] = bf_lo(u.x); zt[d0 + 1][col] = bf_hi(u.x);
      zt[d0 + 2][col] = bf_lo(u.y); zt[d0 + 3][col] = bf_hi(u.y);
      zt[d0 + 4][col] = bf_lo(u.z); zt[d0 + 5][col] = bf_hi(u.z);
      zt[d0 + 6][col] = bf_lo(u.w); zt[d0 + 7][col] = bf_hi(u.w);
    }
  } else {
    const float4* src = (const float4*)((const float*)z + row0 * DIM);
    #pragma unroll
    for (int j = 0; j < 4; ++j) {
      int idx = tid + THREADS * j;              // [0,2048)
      int row = idx >> 4, d0 = (idx & 15) * 4;
      int col = zcol(row);
      float4 v = src[idx];
      zt[d0 + 0][col] = v.x; zt[d0 + 1][col] = v.y;
      zt[d0 + 2][col] = v.z; zt[d0 + 3][col] = v.w;
    }
  }
  __syncthreads();

  // zz per row = np.sum(z*z) in f32, numpy pairwise order over products.
  if (tid < ROWS_PER_BLOCK) {
    const int c0 = zcol(tid);
    s_zz[tid] = np_sum64([&](int d) { float v = zt[d][c0]; return __fmul_rn(v, v); });
  }

  float best[8] = {3.4e38f, 3.4e38f, 3.4e38f, 3.4e38f,
                   3.4e38f, 3.4e38f, 3.4e38f, 3.4e38f};
  int bk[8] = {0, 0, 0, 0, 0, 0, 0, 0};
  float acc[8][8];
  #pragma unroll
  for (int ri = 0; ri < 8; ++ri)
    #pragma unroll
    for (int ki = 0; ki < 8; ++ki) acc[ri][ki] = 0.0f;

  for (int c = 0; c < NCHUNK; ++c) {
    __syncthreads();  // prev chunk compute done (c=0: zz done)
    // stage chunk c transposed (exact f32 values)
    if (cb_bf16) {
      const uint4* src = (const uint4*)((const uint16_t*)cb + (size_t)c * CHUNK * DIM);
      #pragma unroll
      for (int j = 0; j < 4; ++j) {
        int idx = tid + THREADS * j;            // [0,2048)
        int kc = idx >> 3, d0 = (idx & 7) * 8;
        uint4 u = src[idx];
        ct[d0 + 0][kc] = bf_lo(u.x); ct[d0 + 1][kc] = bf_hi(u.x);
        ct[d0 + 2][kc] = bf_lo(u.y); ct[d0 + 3][kc] = bf_hi(u.y);
        ct[d0 + 4][kc] = bf_lo(u.z); ct[d0 + 5][kc] = bf_hi(u.z);
        ct[d0 + 6][kc] = bf_lo(u.w); ct[d0 + 7][kc] = bf_hi(u.w);
      }
    } else {
      const float4* src = (const float4*)((const float*)cb + (size_t)c * CHUNK * DIM);
      #pragma unroll
      for (int j = 0; j < 8; ++j) {
        int idx = tid + THREADS * j;            // [0,4096)
        int kc = idx >> 4, d0 = (idx & 15) * 4;
        float4 v = src[idx];
        ct[d0 + 0][kc] = v.x; ct[d0 + 1][kc] = v.y;
        ct[d0 + 2][kc] = v.z; ct[d0 + 3][kc] = v.w;
      }
    }
    __syncthreads();

    // inner: per d, 4 ds_read_b128 feed 128 VALU ops (non-fused; per
    // (row,code) chain is ascending d == reference einsum order).
    #pragma unroll 4
    for (int d = 0; d < DIM; ++d) {
      float4 zA = *(const float4*)&zt[d][TR * 4];        // rows 8TR+0..3
      float4 zB = *(const float4*)&zt[d][TR * 4 + 64];   // rows 8TR+4..7
      float4 cA = *(const float4*)&ct[d][TK * 8];
      float4 cB = *(const float4*)&ct[d][TK * 8 + 4];
      float zv[8] = {zA.x, zA.y, zA.z, zA.w, zB.x, zB.y, zB.z, zB.w};
      float cv[8] = {cA.x, cA.y, cA.z, cA.w, cB.x, cB.y, cB.z, cB.w};
      #pragma unroll
      for (int ri = 0; ri < 8; ++ri)
        #pragma unroll
        for (int ki = 0; ki < 8; ++ki)
          acc[ri][ki] = __fadd_rn(acc[ri][ki], __fmul_rn(zv[ri], cv[ki]));
    }

    // epilogue: d2 = fl(fl(zz+cc) - fl(2*g)); per-thread k ascending, strict <.
    #pragma unroll
    for (int ri = 0; ri < 8; ++ri) {
      const float zzr = s_zz[TR * 8 + ri];
      #pragma unroll
      for (int ki = 0; ki < 8; ++ki) {
        const int k = c * CHUNK + TK * 8 + ki;
        float e = __fsub_rn(__fadd_rn(zzr, s_cc[k]), __fmul_rn(2.0f, acc[ri][ki]));
        if (e < best[ri]) { best[ri] = e; bk[ri] = k; }
        acc[ri][ki] = 0.0f;
      }
    }
  }

  // wave-level lexicographic merge across the 4 TK values in this wave
  // (lanes l, l^16, l^32 share TR). Lex (d2,k) min is assoc/comm -> any
  // merge order == global first-index argmin.
  #pragma unroll
  for (int ri = 0; ri < 8; ++ri) {
    float v = best[ri]; int k = bk[ri];
    {
      float v2 = __shfl_xor(v, 16, 64); int k2 = __shfl_xor(k, 16, 64);
      if (v2 < v || (v2 == v && k2 < k)) { v = v2; k = k2; }
      v2 = __shfl_xor(v, 32, 64); k2 = __shfl_xor(k, 32, 64);
      if (v2 < v || (v2 == v && k2 < k)) { v = v2; k = k2; }
    }
    best[ri] = v; bk[ri] = k;
  }
  {
    const int lane = tid & 63, wv = tid >> 6;
    if (lane < 16) {
      #pragma unroll
      for (int ri = 0; ri < 8; ++ri) {
        s_bestW[wv][lane * 8 + ri] = best[ri];   // lane == TR here
        s_kW[wv][lane * 8 + ri] = bk[ri];
      }
    }
  }
  __syncthreads();

  if (tid < ROWS_PER_BLOCK) {
    // final lex merge across the 8 waves
    float b = 3.4e38f;
    int bbk = 0x7FFFFFFF;
    #pragma unroll
    for (int p = 0; p < 8; ++p) {
      float v = s_bestW[p][tid];
      int vk = s_kW[p][tid];
      if (v < b || (v == b && vk < bbk)) { b = v; bbk = vk; }
    }
    s_win[tid] = bbk;
    // Exact squared distance of the winner (fp64); exact z from zt column.
    const int c0 = zcol(tid);
    double acc2 = 0.0;
    if (cb_bf16) {
      const uint16_t* cp = (const uint16_t*)cb + (size_t)bbk * DIM;
      for (int d = 0; d < DIM; ++d) {
        double df = (double)zt[d][c0] - (double)bfbits((uint32_t)cp[d]);
        acc2 = fma(df, df, acc2);
      }
    } else {
      const float* cp = (const float*)cb + (size_t)bbk * DIM;
      for (int d = 0; d < DIM; ++d) {
        double df = (double)zt[d][c0] - (double)cp[d];
        acc2 = fma(df, df, acc2);
      }
    }
    s_loss[tid] = acc2;
    out[(size_t)N_ELEMS + 1 + row0 + tid] = round_bf16((float)bbk);
  }
  __syncthreads();

  // z_q write: 128 rows x 64 dims = 8192 floats, 512 threads x 16, coalesced.
  const size_t base = row0 * DIM;
  #pragma unroll
  for (int j = 0; j < 16; ++j) {
    int idx = tid + THREADS * j;
    int rr = idx >> 6, dd = idx & 63;
    int w = s_win[rr];
    float v;
    if (cb_bf16) v = bfbits((uint32_t)((const uint16_t*)cb)[(size_t)w * DIM + dd]);
    else         v = round_bf16(((const float*)cb)[(size_t)w * DIM + dd]);
    out[base + idx] = v;
  }

  if (tid == 0) {
    double s = 0.0;
    for (int i = 0; i < ROWS_PER_BLOCK; ++i) s += s_loss[i];
    partials[blockIdx.x] = s;
  }
}

__global__ __launch_bounds__(256) void vq_loss_kernel(
    const double* __restrict__ partials, float* __restrict__ out) {
  __shared__ double sh[256];
  const int tid = threadIdx.x;
  double s = 0.0;
  for (int i = tid; i < NBLOCKS; i += 256) s += partials[i];
  sh[tid] = s;
  __syncthreads();
  if (tid == 0) {
    double t = 0.0;
    for (int i = 0; i < 256; ++i) t += sh[i];
    out[N_ELEMS] = round_bf16((float)(1.25 * t / (double)N_ELEMS));
  }
}

extern "C" void kernel_launch(void* const* d_in, const int* in_sizes, int n_in,
                              void* d_out, int out_size, void* d_ws, size_t ws_size,
                              hipStream_t stream) {
  const void* z  = d_in[0];
  const void* cb = d_in[1];
  float* out = (float*)d_out;
  uint8_t* ws = (uint8_t*)d_ws;
  float* cc = (float*)ws;
  int* flags = (int*)(ws + 4096);
  double* partials = (double*)(ws + 8192);

  vq_prep_kernel<<<K_CODES / 256, 256, 0, stream>>>(z, cb, cc, flags);
  vq_kernel<<<NBLOCKS, THREADS, 0, stream>>>(z, cb, cc, flags, out, partials);
  vq_loss_kernel<<<1, 256, 0, stream>>>(partials, out);
}

// Round 12
// 140.920 us; speedup vs baseline: 2.7859x; 1.0084x over previous
//
#include <hip/hip_runtime.h>
#include <stdint.h>

// VectorQuantizer: z [32768,64], codebook [1024,64] (dtype sniffed bf16/f32).
// d_out FLOAT32: z_q_st [2097152] ++ loss [1] ++ indices [32768].
// Bit-exact replication of the reference f32 arithmetic (numpy pairwise sums,
// sequential non-fused dot, f32 final adds, first-index argmin).
//
// R15 vs R14 (vq 85.7us but TOTAL 142us): total-vq ~= 56us = prep kernel +
// loss kernel + inter-kernel gaps (~40% of end-to-end). Fuse prep INTO vq:
// each block sniffs dtypes itself (L2-hot probes) and computes s_cc[1024]
// from global at start (2 codes/thread, 8-accumulator streaming np_sum64,
// no cv[64] register array), overlapped with zt staging. Hot loop/staging/
// merge identical to R14 (harness-verified). Loss kernel kept (1 block).
#define N_ROWS 32768
#define DIM 64
#define K_CODES 1024
#define ROWS_PER_BLOCK 128
#define THREADS 512
#define CHUNK 256
#define NCHUNK (K_CODES / CHUNK)              // 4
#define NBLOCKS (N_ROWS / ROWS_PER_BLOCK)     // 256
#define N_ELEMS (N_ROWS * DIM)                // 2097152
#define ZT_STRIDE 128
#define CT_STRIDE 256

// workspace layout (bytes):
// [8192,10240)  double partials[NBLOCKS=256]

__device__ __forceinline__ float bfbits(uint32_t b) { return __uint_as_float(b << 16); }
__device__ __forceinline__ float bf_lo(uint32_t u) { return __uint_as_float(u << 16); }
__device__ __forceinline__ float bf_hi(uint32_t u) { return __uint_as_float(u & 0xFFFF0000u); }

// round f32 -> nearest bf16 value, returned AS f32 (RNE; finite inputs).
__device__ __forceinline__ float round_bf16(float f) {
  uint32_t u = __float_as_uint(f);
  uint32_t r = ((u + 0x7FFFu + ((u >> 16) & 1u)) >> 16) << 16;
  return __uint_as_float(r);
}

// zt split-plane column: row = 8*TR + s -> col = TR*4 + (s>>2)*64 + (s&3).
__device__ __forceinline__ int zcol(int row) {
  return ((row >> 3) << 2) + (((row >> 2) & 1) << 6) + (row & 3);
}

// numpy pairwise_sum for n=64 (8 accumulators, 8 rounds, numpy's combine tree).
template <typename F>
__device__ __forceinline__ float np_sum64(F get) {
  float r0 = get(0), r1 = get(1), r2 = get(2), r3 = get(3);
  float r4 = get(4), r5 = get(5), r6 = get(6), r7 = get(7);
  for (int i = 8; i < 64; i += 8) {
    r0 = __fadd_rn(r0, get(i + 0)); r1 = __fadd_rn(r1, get(i + 1));
    r2 = __fadd_rn(r2, get(i + 2)); r3 = __fadd_rn(r3, get(i + 3));
    r4 = __fadd_rn(r4, get(i + 4)); r5 = __fadd_rn(r5, get(i + 5));
    r6 = __fadd_rn(r6, get(i + 6)); r7 = __fadd_rn(r7, get(i + 7));
  }
  return __fadd_rn(__fadd_rn(__fadd_rn(r0, r1), __fadd_rn(r2, r3)),
                   __fadd_rn(__fadd_rn(r4, r5), __fadd_rn(r6, r7)));
}

// Thread tile: TR = tid&15 (8 rows), TK = tid>>4 in [0,32) (8 codes of 256).
__global__ __launch_bounds__(THREADS, 1) void vq_kernel(
    const void* __restrict__ z, const void* __restrict__ cb,
    float* __restrict__ out, double* __restrict__ partials) {
  const int tid = threadIdx.x;

  __shared__ int s_cnt[2];
  __shared__ float zt[DIM][ZT_STRIDE];          // 32 KB, split-plane cols
  __shared__ float ct[DIM][CT_STRIDE];          // 64 KB
  __shared__ float s_cc[K_CODES];               // 4 KB
  __shared__ float s_zz[ROWS_PER_BLOCK];        // 512 B
  __shared__ float s_bestW[8][ROWS_PER_BLOCK];  // 4 KB
  __shared__ int   s_kW[8][ROWS_PER_BLOCK];     // 4 KB
  __shared__ int   s_win[ROWS_PER_BLOCK];       // 512 B
  __shared__ double s_loss[ROWS_PER_BLOCK];     // 1 KB

  // ---- per-block dtype sniff (identical logic/result in every block) ----
  if (tid < 2) s_cnt[tid] = 0;
  __syncthreads();
  if (tid < 128) {
    uint32_t wc = ((const uint32_t*)cb)[(size_t)tid * 255];
    float vc = fabsf(bfbits(wc & 0xFFFFu));
    if (vc == 0.0f || (vc > 5.9e-8f && vc < 32.0f)) atomicAdd(&s_cnt[1], 1);
    uint32_t wz = ((const uint32_t*)z)[(size_t)tid * 8191];
    float vz = fabsf(bfbits(wz & 0xFFFFu));
    if (vz == 0.0f || (vz > 5.9e-8f && vz < 32.0f)) atomicAdd(&s_cnt[0], 1);
  }
  __syncthreads();
  const bool z_bf16  = s_cnt[0] >= 96;
  const bool cb_bf16 = s_cnt[1] >= 96;

  const int TR = tid & 15;
  const int TK = tid >> 4;
  const size_t row0 = (size_t)blockIdx.x * ROWS_PER_BLOCK;

  // ---- s_cc from global: 2 codes/thread, 8-acc streaming numpy pairwise ----
  // Same add sequence as np_sum64 over c*c (r_i += fl(c_{8j+i}^2), same tree).
  for (int kk = tid; kk < K_CODES; kk += THREADS) {
    float r0, r1, r2, r3, r4, r5, r6, r7;
    if (cb_bf16) {
      const uint4* cp = (const uint4*)((const uint16_t*)cb + (size_t)kk * DIM);
      uint4 u = cp[0];
      r0 = __fmul_rn(bf_lo(u.x), bf_lo(u.x)); r1 = __fmul_rn(bf_hi(u.x), bf_hi(u.x));
      r2 = __fmul_rn(bf_lo(u.y), bf_lo(u.y)); r3 = __fmul_rn(bf_hi(u.y), bf_hi(u.y));
      r4 = __fmul_rn(bf_lo(u.z), bf_lo(u.z)); r5 = __fmul_rn(bf_hi(u.z), bf_hi(u.z));
      r6 = __fmul_rn(bf_lo(u.w), bf_lo(u.w)); r7 = __fmul_rn(bf_hi(u.w), bf_hi(u.w));
      #pragma unroll
      for (int j = 1; j < 8; ++j) {
        u = cp[j];
        r0 = __fadd_rn(r0, __fmul_rn(bf_lo(u.x), bf_lo(u.x)));
        r1 = __fadd_rn(r1, __fmul_rn(bf_hi(u.x), bf_hi(u.x)));
        r2 = __fadd_rn(r2, __fmul_rn(bf_lo(u.y), bf_lo(u.y)));
        r3 = __fadd_rn(r3, __fmul_rn(bf_hi(u.y), bf_hi(u.y)));
        r4 = __fadd_rn(r4, __fmul_rn(bf_lo(u.z), bf_lo(u.z)));
        r5 = __fadd_rn(r5, __fmul_rn(bf_hi(u.z), bf_hi(u.z)));
        r6 = __fadd_rn(r6, __fmul_rn(bf_lo(u.w), bf_lo(u.w)));
        r7 = __fadd_rn(r7, __fmul_rn(bf_hi(u.w), bf_hi(u.w)));
      }
    } else {
      const float4* cp = (const float4*)((const float*)cb + (size_t)kk * DIM);
      float4 a = cp[0], b = cp[1];
      r0 = __fmul_rn(a.x, a.x); r1 = __fmul_rn(a.y, a.y);
      r2 = __fmul_rn(a.z, a.z); r3 = __fmul_rn(a.w, a.w);
      r4 = __fmul_rn(b.x, b.x); r5 = __fmul_rn(b.y, b.y);
      r6 = __fmul_rn(b.z, b.z); r7 = __fmul_rn(b.w, b.w);
      #pragma unroll
      for (int j = 1; j < 8; ++j) {
        a = cp[2 * j]; b = cp[2 * j + 1];
        r0 = __fadd_rn(r0, __fmul_rn(a.x, a.x));
        r1 = __fadd_rn(r1, __fmul_rn(a.y, a.y));
        r2 = __fadd_rn(r2, __fmul_rn(a.z, a.z));
        r3 = __fadd_rn(r3, __fmul_rn(a.w, a.w));
        r4 = __fadd_rn(r4, __fmul_rn(b.x, b.x));
        r5 = __fadd_rn(r5, __fmul_rn(b.y, b.y));
        r6 = __fadd_rn(r6, __fmul_rn(b.z, b.z));
        r7 = __fadd_rn(r7, __fmul_rn(b.w, b.w));
      }
    }
    s_cc[kk] = __fadd_rn(__fadd_rn(__fadd_rn(r0, r1), __fadd_rn(r2, r3)),
                         __fadd_rn(__fadd_rn(r4, r5), __fadd_rn(r6, r7)));
  }

  // ---- stage z transposed into split-plane layout (exact f32 values) ----
  if (z_bf16) {
    const uint4* src = (const uint4*)((const uint16_t*)z + row0 * DIM);
    #pragma unroll
    for (int j = 0; j < 2; ++j) {
      int idx = tid + THREADS * j;              // [0,1024)
      int row = idx >> 3, d0 = (idx & 7) * 8;
      int col = zcol(row);
      uint4 u = src[idx];
      zt[d0 + 0][col] = bf_lo(u.x); zt[d0 + 1][col] = bf_hi(u.x);
      zt[d0 + 2][col] = bf_lo(u.y); zt[d0 + 3][col] = bf_hi(u.y);
      zt[d0 + 4][col] = bf_lo(u.z); zt[d0 + 5][col] = bf_hi(u.z);
      zt[d0 + 6][col] = bf_lo(u.w); zt[d0 + 7][col] = bf_hi(u.w);
    }
  } else {
    const float4* src = (const float4*)((const float*)z + row0 * DIM);
    #pragma unroll
    for (int j = 0; j < 4; ++j) {
      int idx = tid + THREADS * j;              // [0,2048)
      int row = idx >> 4, d0 = (idx & 15) * 4;
      int col = zcol(row);
      float4 v = src[idx];
      zt[d0 + 0][col] = v.x; zt[d0 + 1][col] = v.y;
      zt[d0 + 2][col] = v.z; zt[d0 + 3][col] = v.w;
    }
  }
  __syncthreads();

  // zz per row = np.sum(z*z) in f32, numpy pairwise order over products.
  if (tid < ROWS_PER_BLOCK) {
    const int c0 = zcol(tid);
    s_zz[tid] = np_sum64([&](int d) { float v = zt[d][c0]; return __fmul_rn(v, v); });
  }

  float best[8] = {3.4e38f, 3.4e38f, 3.4e38f, 3.4e38f,
                   3.4e38f, 3.4e38f, 3.4e38f, 3.4e38f};
  int bk[8] = {0, 0, 0, 0, 0, 0, 0, 0};
  float acc[8][8];
  #pragma unroll
  for (int ri = 0; ri < 8; ++ri)
    #pragma unroll
    for (int ki = 0; ki < 8; ++ki) acc[ri][ki] = 0.0f;

  for (int c = 0; c < NCHUNK; ++c) {
    __syncthreads();  // prev chunk compute done (c=0: zz done)
    // stage chunk c transposed (exact f32 values)
    if (cb_bf16) {
      const uint4* src = (const uint4*)((const uint16_t*)cb + (size_t)c * CHUNK * DIM);
      #pragma unroll
      for (int j = 0; j < 4; ++j) {
        int idx = tid + THREADS * j;            // [0,2048)
        int kc = idx >> 3, d0 = (idx & 7) * 8;
        uint4 u = src[idx];
        ct[d0 + 0][kc] = bf_lo(u.x); ct[d0 + 1][kc] = bf_hi(u.x);
        ct[d0 + 2][kc] = bf_lo(u.y); ct[d0 + 3][kc] = bf_hi(u.y);
        ct[d0 + 4][kc] = bf_lo(u.z); ct[d0 + 5][kc] = bf_hi(u.z);
        ct[d0 + 6][kc] = bf_lo(u.w); ct[d0 + 7][kc] = bf_hi(u.w);
      }
    } else {
      const float4* src = (const float4*)((const float*)cb + (size_t)c * CHUNK * DIM);
      #pragma unroll
      for (int j = 0; j < 8; ++j) {
        int idx = tid + THREADS * j;            // [0,4096)
        int kc = idx >> 4, d0 = (idx & 15) * 4;
        float4 v = src[idx];
        ct[d0 + 0][kc] = v.x; ct[d0 + 1][kc] = v.y;
        ct[d0 + 2][kc] = v.z; ct[d0 + 3][kc] = v.w;
      }
    }
    __syncthreads();

    // inner: per d, 4 ds_read_b128 feed 128 VALU ops (non-fused; per
    // (row,code) chain is ascending d == reference einsum order).
    #pragma unroll 4
    for (int d = 0; d < DIM; ++d) {
      float4 zA = *(const float4*)&zt[d][TR * 4];        // rows 8TR+0..3
      float4 zB = *(const float4*)&zt[d][TR * 4 + 64];   // rows 8TR+4..7
      float4 cA = *(const float4*)&ct[d][TK * 8];
      float4 cB = *(const float4*)&ct[d][TK * 8 + 4];
      float zv[8] = {zA.x, zA.y, zA.z, zA.w, zB.x, zB.y, zB.z, zB.w};
      float cv[8] = {cA.x, cA.y, cA.z, cA.w, cB.x, cB.y, cB.z, cB.w};
      #pragma unroll
      for (int ri = 0; ri < 8; ++ri)
        #pragma unroll
        for (int ki = 0; ki < 8; ++ki)
          acc[ri][ki] = __fadd_rn(acc[ri][ki], __fmul_rn(zv[ri], cv[ki]));
    }

    // epilogue: d2 = fl(fl(zz+cc) - fl(2*g)); per-thread k ascending, strict <.
    #pragma unroll
    for (int ri = 0; ri < 8; ++ri) {
      const float zzr = s_zz[TR * 8 + ri];
      #pragma unroll
      for (int ki = 0; ki < 8; ++ki) {
        const int k = c * CHUNK + TK * 8 + ki;
        float e = __fsub_rn(__fadd_rn(zzr, s_cc[k]), __fmul_rn(2.0f, acc[ri][ki]));
        if (e < best[ri]) { best[ri] = e; bk[ri] = k; }
        acc[ri][ki] = 0.0f;
      }
    }
  }

  // wave-level lexicographic merge across the 4 TK values in this wave
  // (lanes l, l^16, l^32 share TR). Lex (d2,k) min is assoc/comm -> any
  // merge order == global first-index argmin.
  #pragma unroll
  for (int ri = 0; ri < 8; ++ri) {
    float v = best[ri]; int k = bk[ri];
    {
      float v2 = __shfl_xor(v, 16, 64); int k2 = __shfl_xor(k, 16, 64);
      if (v2 < v || (v2 == v && k2 < k)) { v = v2; k = k2; }
      v2 = __shfl_xor(v, 32, 64); k2 = __shfl_xor(k, 32, 64);
      if (v2 < v || (v2 == v && k2 < k)) { v = v2; k = k2; }
    }
    best[ri] = v; bk[ri] = k;
  }
  {
    const int lane = tid & 63, wv = tid >> 6;
    if (lane < 16) {
      #pragma unroll
      for (int ri = 0; ri < 8; ++ri) {
        s_bestW[wv][lane * 8 + ri] = best[ri];   // lane == TR here
        s_kW[wv][lane * 8 + ri] = bk[ri];
      }
    }
  }
  __syncthreads();

  if (tid < ROWS_PER_BLOCK) {
    // final lex merge across the 8 waves
    float b = 3.4e38f;
    int bbk = 0x7FFFFFFF;
    #pragma unroll
    for (int p = 0; p < 8; ++p) {
      float v = s_bestW[p][tid];
      int vk = s_kW[p][tid];
      if (v < b || (v == b && vk < bbk)) { b = v; bbk = vk; }
    }
    s_win[tid] = bbk;
    // Exact squared distance of the winner (fp64); exact z from zt column.
    const int c0 = zcol(tid);
    double acc2 = 0.0;
    if (cb_bf16) {
      const uint16_t* cp = (const uint16_t*)cb + (size_t)bbk * DIM;
      for (int d = 0; d < DIM; ++d) {
        double df = (double)zt[d][c0] - (double)bfbits((uint32_t)cp[d]);
        acc2 = fma(df, df, acc2);
      }
    } else {
      const float* cp = (const float*)cb + (size_t)bbk * DIM;
      for (int d = 0; d < DIM; ++d) {
        double df = (double)zt[d][c0] - (double)cp[d];
        acc2 = fma(df, df, acc2);
      }
    }
    s_loss[tid] = acc2;
    out[(size_t)N_ELEMS + 1 + row0 + tid] = round_bf16((float)bbk);
  }
  __syncthreads();

  // z_q write: 128 rows x 64 dims = 8192 floats, 512 threads x 16, coalesced.
  const size_t base = row0 * DIM;
  #pragma unroll
  for (int j = 0; j < 16; ++j) {
    int idx = tid + THREADS * j;
    int rr = idx >> 6, dd = idx & 63;
    int w = s_win[rr];
    float v;
    if (cb_bf16) v = bfbits((uint32_t)((const uint16_t*)cb)[(size_t)w * DIM + dd]);
    else         v = round_bf16(((const float*)cb)[(size_t)w * DIM + dd]);
    out[base + idx] = v;
  }

  if (tid == 0) {
    double s = 0.0;
    for (int i = 0; i < ROWS_PER_BLOCK; ++i) s += s_loss[i];
    partials[blockIdx.x] = s;
  }
}

__global__ __launch_bounds__(256) void vq_loss_kernel(
    const double* __restrict__ partials, float* __restrict__ out) {
  __shared__ double sh[256];
  const int tid = threadIdx.x;
  double s = 0.0;
  for (int i = tid; i < NBLOCKS; i += 256) s += partials[i];
  sh[tid] = s;
  __syncthreads();
  if (tid == 0) {
    double t = 0.0;
    for (int i = 0; i < 256; ++i) t += sh[i];
    out[N_ELEMS] = round_bf16((float)(1.25 * t / (double)N_ELEMS));
  }
}

extern "C" void kernel_launch(void* const* d_in, const int* in_sizes, int n_in,
                              void* d_out, int out_size, void* d_ws, size_t ws_size,
                              hipStream_t stream) {
  const void* z  = d_in[0];
  const void* cb = d_in[1];
  float* out = (float*)d_out;
  uint8_t* ws = (uint8_t*)d_ws;
  double* partials = (double*)(ws + 8192);

  vq_kernel<<<NBLOCKS, THREADS, 0, stream>>>(z, cb, out, partials);
  vq_loss_kernel<<<1, 256, 0, stream>>>(partials, out);
}

// Round 13
// 137.262 us; speedup vs baseline: 2.8602x; 1.0267x over previous
//
#include <hip/hip_runtime.h>
#include <stdint.h>

// VectorQuantizer: z [32768,64], codebook [1024,64] (dtype sniffed bf16/f32).
// d_out FLOAT32: z_q_st [2097152] ++ loss [1] ++ indices [32768].
// Bit-exact replication of the reference f32 arithmetic (numpy pairwise sums,
// sequential non-fused dot, f32 final adds, first-index argmin).
//
// R16 vs R15 (total 140.9, vq 93, 9.06M LDS bank conflicts ~15% of wall):
//  1) XOR-swizzle both LDS layouts (write AND read, same involution):
//     zt col ^= ((d>>3)&7)<<2 (16-way -> 2-way on staging stores),
//     ct col ^= ((d>>3)&3)<<3 (8-way -> 2-way). Read side stays b128-
//     contiguous+broadcast since d>>3 is instruction-uniform. Placement only.
//  2) Loss fused via last-block pattern (partials -> threadfence -> counter
//     atomic; last block reduces) -> single dispatch (each dispatch ~8us).
#define N_ROWS 32768
#define DIM 64
#define K_CODES 1024
#define ROWS_PER_BLOCK 128
#define THREADS 512
#define CHUNK 256
#define NCHUNK (K_CODES / CHUNK)              // 4
#define NBLOCKS (N_ROWS / ROWS_PER_BLOCK)     // 256
#define N_ELEMS (N_ROWS * DIM)                // 2097152
#define ZT_STRIDE 128
#define CT_STRIDE 256

// workspace layout (bytes):
// [4096,4100)   uint counter (memset to 0 per launch)
// [8192,10240)  double partials[NBLOCKS=256]

__device__ __forceinline__ float bfbits(uint32_t b) { return __uint_as_float(b << 16); }
__device__ __forceinline__ float bf_lo(uint32_t u) { return __uint_as_float(u << 16); }
__device__ __forceinline__ float bf_hi(uint32_t u) { return __uint_as_float(u & 0xFFFF0000u); }

// round f32 -> nearest bf16 value, returned AS f32 (RNE; finite inputs).
__device__ __forceinline__ float round_bf16(float f) {
  uint32_t u = __float_as_uint(f);
  uint32_t r = ((u + 0x7FFFu + ((u >> 16) & 1u)) >> 16) << 16;
  return __uint_as_float(r);
}

// zt split-plane column: row = 8*TR + s -> col = TR*4 + (s>>2)*64 + (s&3).
__device__ __forceinline__ int zcol(int row) {
  return ((row >> 3) << 2) + (((row >> 2) & 1) << 6) + (row & 3);
}

// numpy pairwise_sum for n=64 (8 accumulators, 8 rounds, numpy's combine tree).
template <typename F>
__device__ __forceinline__ float np_sum64(F get) {
  float r0 = get(0), r1 = get(1), r2 = get(2), r3 = get(3);
  float r4 = get(4), r5 = get(5), r6 = get(6), r7 = get(7);
  for (int i = 8; i < 64; i += 8) {
    r0 = __fadd_rn(r0, get(i + 0)); r1 = __fadd_rn(r1, get(i + 1));
    r2 = __fadd_rn(r2, get(i + 2)); r3 = __fadd_rn(r3, get(i + 3));
    r4 = __fadd_rn(r4, get(i + 4)); r5 = __fadd_rn(r5, get(i + 5));
    r6 = __fadd_rn(r6, get(i + 6)); r7 = __fadd_rn(r7, get(i + 7));
  }
  return __fadd_rn(__fadd_rn(__fadd_rn(r0, r1), __fadd_rn(r2, r3)),
                   __fadd_rn(__fadd_rn(r4, r5), __fadd_rn(r6, r7)));
}

// Thread tile: TR = tid&15 (8 rows), TK = tid>>4 in [0,32) (8 codes of 256).
__global__ __launch_bounds__(THREADS, 1) void vq_kernel(
    const void* __restrict__ z, const void* __restrict__ cb,
    float* __restrict__ out, double* __restrict__ partials,
    unsigned int* __restrict__ counter) {
  const int tid = threadIdx.x;

  __shared__ int s_cnt[2];
  __shared__ int s_last;
  __shared__ float zt[DIM][ZT_STRIDE];          // 32 KB, split-plane + XOR swz
  __shared__ float ct[DIM][CT_STRIDE];          // 64 KB, XOR swz
  __shared__ float s_cc[K_CODES];               // 4 KB
  __shared__ float s_zz[ROWS_PER_BLOCK];        // 512 B
  __shared__ float s_bestW[8][ROWS_PER_BLOCK];  // 4 KB
  __shared__ int   s_kW[8][ROWS_PER_BLOCK];     // 4 KB
  __shared__ int   s_win[ROWS_PER_BLOCK];       // 512 B
  __shared__ double s_loss[ROWS_PER_BLOCK];     // 1 KB

  // ---- per-block dtype sniff (identical logic/result in every block) ----
  if (tid < 2) s_cnt[tid] = 0;
  __syncthreads();
  if (tid < 128) {
    uint32_t wc = ((const uint32_t*)cb)[(size_t)tid * 255];
    float vc = fabsf(bfbits(wc & 0xFFFFu));
    if (vc == 0.0f || (vc > 5.9e-8f && vc < 32.0f)) atomicAdd(&s_cnt[1], 1);
    uint32_t wz = ((const uint32_t*)z)[(size_t)tid * 8191];
    float vz = fabsf(bfbits(wz & 0xFFFFu));
    if (vz == 0.0f || (vz > 5.9e-8f && vz < 32.0f)) atomicAdd(&s_cnt[0], 1);
  }
  __syncthreads();
  const bool z_bf16  = s_cnt[0] >= 96;
  const bool cb_bf16 = s_cnt[1] >= 96;

  const int TR = tid & 15;
  const int TK = tid >> 4;
  const size_t row0 = (size_t)blockIdx.x * ROWS_PER_BLOCK;

  // ---- s_cc from global: 2 codes/thread, 8-acc streaming numpy pairwise ----
  for (int kk = tid; kk < K_CODES; kk += THREADS) {
    float r0, r1, r2, r3, r4, r5, r6, r7;
    if (cb_bf16) {
      const uint4* cp = (const uint4*)((const uint16_t*)cb + (size_t)kk * DIM);
      uint4 u = cp[0];
      r0 = __fmul_rn(bf_lo(u.x), bf_lo(u.x)); r1 = __fmul_rn(bf_hi(u.x), bf_hi(u.x));
      r2 = __fmul_rn(bf_lo(u.y), bf_lo(u.y)); r3 = __fmul_rn(bf_hi(u.y), bf_hi(u.y));
      r4 = __fmul_rn(bf_lo(u.z), bf_lo(u.z)); r5 = __fmul_rn(bf_hi(u.z), bf_hi(u.z));
      r6 = __fmul_rn(bf_lo(u.w), bf_lo(u.w)); r7 = __fmul_rn(bf_hi(u.w), bf_hi(u.w));
      #pragma unroll
      for (int j = 1; j < 8; ++j) {
        u = cp[j];
        r0 = __fadd_rn(r0, __fmul_rn(bf_lo(u.x), bf_lo(u.x)));
        r1 = __fadd_rn(r1, __fmul_rn(bf_hi(u.x), bf_hi(u.x)));
        r2 = __fadd_rn(r2, __fmul_rn(bf_lo(u.y), bf_lo(u.y)));
        r3 = __fadd_rn(r3, __fmul_rn(bf_hi(u.y), bf_hi(u.y)));
        r4 = __fadd_rn(r4, __fmul_rn(bf_lo(u.z), bf_lo(u.z)));
        r5 = __fadd_rn(r5, __fmul_rn(bf_hi(u.z), bf_hi(u.z)));
        r6 = __fadd_rn(r6, __fmul_rn(bf_lo(u.w), bf_lo(u.w)));
        r7 = __fadd_rn(r7, __fmul_rn(bf_hi(u.w), bf_hi(u.w)));
      }
    } else {
      const float4* cp = (const float4*)((const float*)cb + (size_t)kk * DIM);
      float4 a = cp[0], b = cp[1];
      r0 = __fmul_rn(a.x, a.x); r1 = __fmul_rn(a.y, a.y);
      r2 = __fmul_rn(a.z, a.z); r3 = __fmul_rn(a.w, a.w);
      r4 = __fmul_rn(b.x, b.x); r5 = __fmul_rn(b.y, b.y);
      r6 = __fmul_rn(b.z, b.z); r7 = __fmul_rn(b.w, b.w);
      #pragma unroll
      for (int j = 1; j < 8; ++j) {
        a = cp[2 * j]; b = cp[2 * j + 1];
        r0 = __fadd_rn(r0, __fmul_rn(a.x, a.x));
        r1 = __fadd_rn(r1, __fmul_rn(a.y, a.y));
        r2 = __fadd_rn(r2, __fmul_rn(a.z, a.z));
        r3 = __fadd_rn(r3, __fmul_rn(a.w, a.w));
        r4 = __fadd_rn(r4, __fmul_rn(b.x, b.x));
        r5 = __fadd_rn(r5, __fmul_rn(b.y, b.y));
        r6 = __fadd_rn(r6, __fmul_rn(b.z, b.z));
        r7 = __fadd_rn(r7, __fmul_rn(b.w, b.w));
      }
    }
    s_cc[kk] = __fadd_rn(__fadd_rn(__fadd_rn(r0, r1), __fadd_rn(r2, r3)),
                         __fadd_rn(__fadd_rn(r4, r5), __fadd_rn(r6, r7)));
  }

  // ---- stage z transposed, split-plane + XOR swizzle (placement only) ----
  if (z_bf16) {
    const uint4* src = (const uint4*)((const uint16_t*)z + row0 * DIM);
    #pragma unroll
    for (int j = 0; j < 2; ++j) {
      int idx = tid + THREADS * j;              // [0,1024)
      int row = idx >> 3, w = idx & 7, d0 = w * 8;
      int col = zcol(row) ^ (w << 2);           // (d>>3)&7 == w for all 8 d's
      uint4 u = src[idx];
      zt[d0 + 0][col] = bf_lo(u.x); zt[d0 + 1][col] = bf_hi(u.x);
      zt[d0 + 2][col] = bf_lo(u.y); zt[d0 + 3][col] = bf_hi(u.y);
      zt[d0 + 4][col] = bf_lo(u.z); zt[d0 + 5][col] = bf_hi(u.z);
      zt[d0 + 6][col] = bf_lo(u.w); zt[d0 + 7][col] = bf_hi(u.w);
    }
  } else {
    const float4* src = (const float4*)((const float*)z + row0 * DIM);
    #pragma unroll
    for (int j = 0; j < 4; ++j) {
      int idx = tid + THREADS * j;              // [0,2048)
      int row = idx >> 4, d0 = (idx & 15) * 4;
      int col = zcol(row) ^ (((d0 >> 3) & 7) << 2);  // (d>>3) const over 4 d's
      float4 v = src[idx];
      zt[d0 + 0][col] = v.x; zt[d0 + 1][col] = v.y;
      zt[d0 + 2][col] = v.z; zt[d0 + 3][col] = v.w;
    }
  }
  __syncthreads();

  // zz per row = np.sum(z*z) in f32, numpy pairwise order over products.
  if (tid < ROWS_PER_BLOCK) {
    const int c0 = zcol(tid);
    s_zz[tid] = np_sum64([&](int d) {
      float v = zt[d][c0 ^ (((d >> 3) & 7) << 2)];
      return __fmul_rn(v, v); });
  }

  float best[8] = {3.4e38f, 3.4e38f, 3.4e38f, 3.4e38f,
                   3.4e38f, 3.4e38f, 3.4e38f, 3.4e38f};
  int bk[8] = {0, 0, 0, 0, 0, 0, 0, 0};
  float acc[8][8];
  #pragma unroll
  for (int ri = 0; ri < 8; ++ri)
    #pragma unroll
    for (int ki = 0; ki < 8; ++ki) acc[ri][ki] = 0.0f;

  for (int c = 0; c < NCHUNK; ++c) {
    __syncthreads();  // prev chunk compute done (c=0: zz done)
    // stage chunk c transposed + XOR swizzle (placement only)
    if (cb_bf16) {
      const uint4* src = (const uint4*)((const uint16_t*)cb + (size_t)c * CHUNK * DIM);
      #pragma unroll
      for (int j = 0; j < 4; ++j) {
        int idx = tid + THREADS * j;            // [0,2048)
        int kc = idx >> 3, w = idx & 7, d0 = w * 8;
        int col = kc ^ ((w & 3) << 3);          // (d>>3)&3 == w&3 for all 8 d's
        uint4 u = src[idx];
        ct[d0 + 0][col] = bf_lo(u.x); ct[d0 + 1][col] = bf_hi(u.x);
        ct[d0 + 2][col] = bf_lo(u.y); ct[d0 + 3][col] = bf_hi(u.y);
        ct[d0 + 4][col] = bf_lo(u.z); ct[d0 + 5][col] = bf_hi(u.z);
        ct[d0 + 6][col] = bf_lo(u.w); ct[d0 + 7][col] = bf_hi(u.w);
      }
    } else {
      const float4* src = (const float4*)((const float*)cb + (size_t)c * CHUNK * DIM);
      #pragma unroll
      for (int j = 0; j < 8; ++j) {
        int idx = tid + THREADS * j;            // [0,4096)
        int kc = idx >> 4, d0 = (idx & 15) * 4;
        int col = kc ^ (((d0 >> 3) & 3) << 3);
        float4 v = src[idx];
        ct[d0 + 0][col] = v.x; ct[d0 + 1][col] = v.y;
        ct[d0 + 2][col] = v.z; ct[d0 + 3][col] = v.w;
      }
    }
    __syncthreads();

    // inner: per d, 4 ds_read_b128 feed 128 VALU ops (non-fused; per
    // (row,code) chain is ascending d == reference einsum order).
    #pragma unroll 4
    for (int d = 0; d < DIM; ++d) {
      const int zs = ((d >> 3) & 7) << 2;
      const int cs = ((d >> 3) & 3) << 3;
      float4 zA = *(const float4*)&zt[d][(TR << 2) ^ zs];        // rows 8TR+0..3
      float4 zB = *(const float4*)&zt[d][((TR << 2) ^ zs) + 64]; // rows 8TR+4..7
      float4 cA = *(const float4*)&ct[d][(TK << 3) ^ cs];
      float4 cB = *(const float4*)&ct[d][((TK << 3) ^ cs) + 4];
      float zv[8] = {zA.x, zA.y, zA.z, zA.w, zB.x, zB.y, zB.z, zB.w};
      float cv[8] = {cA.x, cA.y, cA.z, cA.w, cB.x, cB.y, cB.z, cB.w};
      #pragma unroll
      for (int ri = 0; ri < 8; ++ri)
        #pragma unroll
        for (int ki = 0; ki < 8; ++ki)
          acc[ri][ki] = __fadd_rn(acc[ri][ki], __fmul_rn(zv[ri], cv[ki]));
    }

    // epilogue: d2 = fl(fl(zz+cc) - fl(2*g)); per-thread k ascending, strict <.
    #pragma unroll
    for (int ri = 0; ri < 8; ++ri) {
      const float zzr = s_zz[TR * 8 + ri];
      #pragma unroll
      for (int ki = 0; ki < 8; ++ki) {
        const int k = c * CHUNK + TK * 8 + ki;
        float e = __fsub_rn(__fadd_rn(zzr, s_cc[k]), __fmul_rn(2.0f, acc[ri][ki]));
        if (e < best[ri]) { best[ri] = e; bk[ri] = k; }
        acc[ri][ki] = 0.0f;
      }
    }
  }

  // wave-level lexicographic merge across the 4 TK values in this wave.
  // Lex (d2,k) min is assoc/comm -> any merge order == first-index argmin.
  #pragma unroll
  for (int ri = 0; ri < 8; ++ri) {
    float v = best[ri]; int k = bk[ri];
    {
      float v2 = __shfl_xor(v, 16, 64); int k2 = __shfl_xor(k, 16, 64);
      if (v2 < v || (v2 == v && k2 < k)) { v = v2; k = k2; }
      v2 = __shfl_xor(v, 32, 64); k2 = __shfl_xor(k, 32, 64);
      if (v2 < v || (v2 == v && k2 < k)) { v = v2; k = k2; }
    }
    best[ri] = v; bk[ri] = k;
  }
  {
    const int lane = tid & 63, wv = tid >> 6;
    if (lane < 16) {
      #pragma unroll
      for (int ri = 0; ri < 8; ++ri) {
        s_bestW[wv][lane * 8 + ri] = best[ri];   // lane == TR here
        s_kW[wv][lane * 8 + ri] = bk[ri];
      }
    }
  }
  __syncthreads();

  if (tid < ROWS_PER_BLOCK) {
    // final lex merge across the 8 waves
    float b = 3.4e38f;
    int bbk = 0x7FFFFFFF;
    #pragma unroll
    for (int p = 0; p < 8; ++p) {
      float v = s_bestW[p][tid];
      int vk = s_kW[p][tid];
      if (v < b || (v == b && vk < bbk)) { b = v; bbk = vk; }
    }
    s_win[tid] = bbk;
    // Exact squared distance of the winner (fp64); exact z from zt column.
    const int c0 = zcol(tid);
    double acc2 = 0.0;
    if (cb_bf16) {
      const uint16_t* cp = (const uint16_t*)cb + (size_t)bbk * DIM;
      for (int d = 0; d < DIM; ++d) {
        double df = (double)zt[d][c0 ^ (((d >> 3) & 7) << 2)]
                  - (double)bfbits((uint32_t)cp[d]);
        acc2 = fma(df, df, acc2);
      }
    } else {
      const float* cp = (const float*)cb + (size_t)bbk * DIM;
      for (int d = 0; d < DIM; ++d) {
        double df = (double)zt[d][c0 ^ (((d >> 3) & 7) << 2)] - (double)cp[d];
        acc2 = fma(df, df, acc2);
      }
    }
    s_loss[tid] = acc2;
    out[(size_t)N_ELEMS + 1 + row0 + tid] = round_bf16((float)bbk);
  }
  __syncthreads();

  // z_q write: 128 rows x 64 dims = 8192 floats, 512 threads x 16, coalesced.
  const size_t base = row0 * DIM;
  #pragma unroll
  for (int j = 0; j < 16; ++j) {
    int idx = tid + THREADS * j;
    int rr = idx >> 6, dd = idx & 63;
    int w = s_win[rr];
    float v;
    if (cb_bf16) v = bfbits((uint32_t)((const uint16_t*)cb)[(size_t)w * DIM + dd]);
    else         v = round_bf16(((const float*)cb)[(size_t)w * DIM + dd]);
    out[base + idx] = v;
  }

  // ---- per-block loss partial + last-block final reduction ----
  if (tid == 0) {
    double s = 0.0;
    for (int i = 0; i < ROWS_PER_BLOCK; ++i) s += s_loss[i];
    partials[blockIdx.x] = s;
    __threadfence();                       // release partials (device scope)
    unsigned int old = atomicAdd(counter, 1u);
    s_last = (old == NBLOCKS - 1) ? 1 : 0;
  }
  __syncthreads();
  if (s_last) {
    __threadfence();                       // acquire all partials
    if (tid < 128) s_loss[tid] = partials[tid] + partials[tid + 128];
    __syncthreads();
    if (tid == 0) {
      double t = 0.0;
      for (int i = 0; i < 128; ++i) t += s_loss[i];
      out[N_ELEMS] = round_bf16((float)(1.25 * t / (double)N_ELEMS));
    }
  }
}

extern "C" void kernel_launch(void* const* d_in, const int* in_sizes, int n_in,
                              void* d_out, int out_size, void* d_ws, size_t ws_size,
                              hipStream_t stream) {
  const void* z  = d_in[0];
  const void* cb = d_in[1];
  float* out = (float*)d_out;
  uint8_t* ws = (uint8_t*)d_ws;
  unsigned int* counter = (unsigned int*)(ws + 4096);
  double* partials = (double*)(ws + 8192);

  hipMemsetAsync(counter, 0, 4, stream);
  vq_kernel<<<NBLOCKS, THREADS, 0, stream>>>(z, cb, out, partials, counter);
}